// Round 8
// baseline (5743.804 us; speedup 1.0000x reference)
//
#include <hip/hip_runtime.h>

#define T_STEPS 512
#define BB 64
#define EE 300
#define EP 320
#define HH 512
#define HB (BB*HH)        // halves per h slot (65536 B)
#define XPSLOT 524288     // bytes per xp slot: 64 rows * 512 cols * 16B (f32 r,z,n,pad)
#define FS 16             // flag stride in ints (64 B): producer-exclusive cache line
#define NCOL 32           // output columns per WG (two 16-col MFMA tiles)
#define CHH 3840          // halves per weight chunk: 3 gates x 32 jj x 40
#define GST 1280          // gate stride in halves
#define DYNLDS 126976     // 16*CHH*2 + 4*512*2 bytes

typedef _Float16 f16x8 __attribute__((ext_vector_type(8)));
typedef float f32x4 __attribute__((ext_vector_type(4)));
typedef int i32x4 __attribute__((ext_vector_type(4)));

__device__ __forceinline__ f32x4 mf(f16x8 a, f16x8 b, f32x4 c) {
  return __builtin_amdgcn_mfma_f32_16x16x32_f16(a, b, c, 0, 0, 0);
}

struct HMat { i32x4 q[16]; };   // 64 VGPRs: one lane's 16 A-fragments of a 16-row tile

// 16 back-to-back PLAIN (L2-cached) 16B loads + FULL drain (write-once h buffers).
#define LOADS16_PLAIN                                                \
    "global_load_dwordx4 %0,  %16, %17\n\t"                          \
    "global_load_dwordx4 %1,  %16, %17 offset:64\n\t"                \
    "global_load_dwordx4 %2,  %16, %17 offset:128\n\t"               \
    "global_load_dwordx4 %3,  %16, %17 offset:192\n\t"               \
    "global_load_dwordx4 %4,  %16, %17 offset:256\n\t"               \
    "global_load_dwordx4 %5,  %16, %17 offset:320\n\t"               \
    "global_load_dwordx4 %6,  %16, %17 offset:384\n\t"               \
    "global_load_dwordx4 %7,  %16, %17 offset:448\n\t"               \
    "global_load_dwordx4 %8,  %16, %17 offset:512\n\t"               \
    "global_load_dwordx4 %9,  %16, %17 offset:576\n\t"               \
    "global_load_dwordx4 %10, %16, %17 offset:640\n\t"               \
    "global_load_dwordx4 %11, %16, %17 offset:704\n\t"               \
    "global_load_dwordx4 %12, %16, %17 offset:768\n\t"               \
    "global_load_dwordx4 %13, %16, %17 offset:832\n\t"               \
    "global_load_dwordx4 %14, %16, %17 offset:896\n\t"               \
    "global_load_dwordx4 %15, %16, %17 offset:960\n\t"               \
    "s_waitcnt vmcnt(0)"

#define HM_OUTS(m) "=v"((m).q[0]), "=v"((m).q[1]), "=v"((m).q[2]), "=v"((m).q[3]),   \
                   "=v"((m).q[4]), "=v"((m).q[5]), "=v"((m).q[6]), "=v"((m).q[7]),   \
                   "=v"((m).q[8]), "=v"((m).q[9]), "=v"((m).q[10]), "=v"((m).q[11]), \
                   "=v"((m).q[12]), "=v"((m).q[13]), "=v"((m).q[14]), "=v"((m).q[15])

__device__ __forceinline__ void load16_plain(HMat& m, const void* base, int voff) {
  asm volatile(LOADS16_PLAIN : HM_OUTS(m) : "v"(voff), "s"(base) : "memory");
}

// fused: 16 PLAIN h-loads (write-once) + 8 sc1 xp loads (reused ring), ONE drain.
// xp layout packs a lane's two column-sets 32B-contiguous: voff + offset:0/16.
#define LOADS16_XP8                                                  \
    "global_load_dwordx4 %0,  %24, %25\n\t"                          \
    "global_load_dwordx4 %1,  %24, %25 offset:64\n\t"                \
    "global_load_dwordx4 %2,  %24, %25 offset:128\n\t"               \
    "global_load_dwordx4 %3,  %24, %25 offset:192\n\t"               \
    "global_load_dwordx4 %4,  %24, %25 offset:256\n\t"               \
    "global_load_dwordx4 %5,  %24, %25 offset:320\n\t"               \
    "global_load_dwordx4 %6,  %24, %25 offset:384\n\t"               \
    "global_load_dwordx4 %7,  %24, %25 offset:448\n\t"               \
    "global_load_dwordx4 %8,  %24, %25 offset:512\n\t"               \
    "global_load_dwordx4 %9,  %24, %25 offset:576\n\t"               \
    "global_load_dwordx4 %10, %24, %25 offset:640\n\t"               \
    "global_load_dwordx4 %11, %24, %25 offset:704\n\t"               \
    "global_load_dwordx4 %12, %24, %25 offset:768\n\t"               \
    "global_load_dwordx4 %13, %24, %25 offset:832\n\t"               \
    "global_load_dwordx4 %14, %24, %25 offset:896\n\t"               \
    "global_load_dwordx4 %15, %24, %25 offset:960\n\t"               \
    "global_load_dwordx4 %16, %26, %30 sc1\n\t"                      \
    "global_load_dwordx4 %17, %26, %30 offset:16 sc1\n\t"            \
    "global_load_dwordx4 %18, %27, %30 sc1\n\t"                      \
    "global_load_dwordx4 %19, %27, %30 offset:16 sc1\n\t"            \
    "global_load_dwordx4 %20, %28, %30 sc1\n\t"                      \
    "global_load_dwordx4 %21, %28, %30 offset:16 sc1\n\t"            \
    "global_load_dwordx4 %22, %29, %30 sc1\n\t"                      \
    "global_load_dwordx4 %23, %29, %30 offset:16 sc1\n\t"            \
    "s_waitcnt vmcnt(0)"

__device__ __forceinline__ void load_h_xp8(HMat& m, f32x4* xp,
                                           const void* hbase, int hvoff,
                                           const void* xbase, const int* vx) {
  asm volatile(LOADS16_XP8
    : HM_OUTS(m),
      "=v"(xp[0]), "=v"(xp[1]), "=v"(xp[2]), "=v"(xp[3]),
      "=v"(xp[4]), "=v"(xp[5]), "=v"(xp[6]), "=v"(xp[7])
    : "v"(hvoff), "s"(hbase), "v"(vx[0]), "v"(vx[1]), "v"(vx[2]), "v"(vx[3]),
      "s"(xbase)
    : "memory");
}

__device__ __forceinline__ void load_xp8(f32x4* xp, const void* xbase, const int* vx) {
  asm volatile(
    "global_load_dwordx4 %0, %8,  %12 sc1\n\t"
    "global_load_dwordx4 %1, %8,  %12 offset:16 sc1\n\t"
    "global_load_dwordx4 %2, %9,  %12 sc1\n\t"
    "global_load_dwordx4 %3, %9,  %12 offset:16 sc1\n\t"
    "global_load_dwordx4 %4, %10, %12 sc1\n\t"
    "global_load_dwordx4 %5, %10, %12 offset:16 sc1\n\t"
    "global_load_dwordx4 %6, %11, %12 sc1\n\t"
    "global_load_dwordx4 %7, %11, %12 offset:16 sc1\n\t"
    "s_waitcnt vmcnt(0)"
    : "=v"(xp[0]), "=v"(xp[1]), "=v"(xp[2]), "=v"(xp[3]),
      "=v"(xp[4]), "=v"(xp[5]), "=v"(xp[6]), "=v"(xp[7])
    : "v"(vx[0]), "v"(vx[1]), "v"(vx[2]), "v"(vx[3]), "s"(xbase) : "memory");
}

// batched x-prefetch: 10 plain cached loads + full drain (x0 is immutable)
__device__ __forceinline__ void loadx10_wait(i32x4* xq, const void* base, int voff) {
  asm volatile(
    "global_load_dwordx4 %0, %10, %11\n\t"
    "global_load_dwordx4 %1, %10, %11 offset:64\n\t"
    "global_load_dwordx4 %2, %10, %11 offset:128\n\t"
    "global_load_dwordx4 %3, %10, %11 offset:192\n\t"
    "global_load_dwordx4 %4, %10, %11 offset:256\n\t"
    "global_load_dwordx4 %5, %10, %11 offset:320\n\t"
    "global_load_dwordx4 %6, %10, %11 offset:384\n\t"
    "global_load_dwordx4 %7, %10, %11 offset:448\n\t"
    "global_load_dwordx4 %8, %10, %11 offset:512\n\t"
    "global_load_dwordx4 %9, %10, %11 offset:576\n\t"
    "s_waitcnt vmcnt(0)"
    : "=v"(xq[0]), "=v"(xq[1]), "=v"(xq[2]), "=v"(xq[3]), "=v"(xq[4]),
      "=v"(xq[5]), "=v"(xq[6]), "=v"(xq[7]), "=v"(xq[8]), "=v"(xq[9])
    : "v"(voff), "s"(base) : "memory");
}

__device__ __forceinline__ f16x8 fragq(i32x4 q) {
  union { i32x4 i; f16x8 v; } x; x.i = q; return x.v;
}

// publish: write-through to MALL so consumers' later L2 fills are fresh
__device__ __forceinline__ void st16_mall(void* p, f16x8 v) {
  i32x4 iv;
  __builtin_memcpy(&iv, &v, 16);
  asm volatile("global_store_dwordx4 %0, %1, off sc0 sc1" :: "v"(p), "v"(iv) : "memory");
}
__device__ __forceinline__ void st16f(void* p, f32x4 v) {
  i32x4 iv;
  __builtin_memcpy(&iv, &v, 16);
  asm volatile("global_store_dwordx4 %0, %1, off sc0 sc1" :: "v"(p), "v"(iv) : "memory");
}
__device__ __forceinline__ void st4_dev(int* p, int v) {
  asm volatile("global_store_dword %0, %1, off sc0 sc1" :: "v"(p), "v"(v) : "memory");
}

// per-WAVE joint poll, producer-exclusive 64B flag lines, 16 producers/condition.
// lanes 0-15 poll A, 16-31 poll B, 32-47 poll C, 48-63 duplicate A.
// Targets <= 0 pass trivially (flags monotone >= 0).
__device__ __forceinline__ void wave_wait16(const int* pa, int ta,
                                            const int* pb, int tb,
                                            const int* pc, int tc_) {
  const int lane = threadIdx.x & 63;
  const int sel = (lane >> 4) & 3;
  const int i16 = lane & 15;
  const int* p = pa; int t = ta;
  if (sel == 1) { p = pb; t = tb; }
  else if (sel == 2) { p = pc; t = tc_; }
  p += i16 * FS;
  for (;;) {
    int v;
    asm volatile("global_load_dword %0, %1, off sc1\n\ts_waitcnt vmcnt(0)"
                 : "=v"(v) : "v"(p) : "memory");
    if (__all(v >= t)) return;
    __builtin_amdgcn_s_sleep(2);
  }
}

__device__ __forceinline__ float sigf(float x) { return 1.f / (1.f + __expf(-x)); }

struct B3 { f16x8 r, z, n; };
// LDS weight read: [chunk][gate(3)][jj(32)][40 halves] — 40-half jj stride spreads
// cols across bank windows (jj*20 + quad*4) mod 32: 2-way max per 16-lane read (free).
__device__ __forceinline__ B3 ldsB(const _Float16* wl, int chunk, int jj, int kq) {
  B3 o;
  const _Float16* p = wl + chunk * CHH + jj * 40 + kq;
  o.r = *(const f16x8*)p;
  o.z = *(const f16x8*)(p + GST);
  o.n = *(const f16x8*)(p + 2 * GST);
  return o;
}

__global__ void prep_x0(const int* __restrict__ texts, const float* __restrict__ emb,
                        _Float16* __restrict__ x0) {
  const size_t N = (size_t)T_STEPS * BB * EP;
  const size_t stride = (size_t)gridDim.x * blockDim.x;
  for (size_t i = (size_t)blockIdx.x * blockDim.x + threadIdx.x; i < N; i += stride) {
    int e = (int)(i % EP);
    size_t tb = i / EP;
    float v = 0.f;
    if (e < EE) v = emb[(size_t)texts[tb] * EE + e];
    x0[i] = (_Float16)v;
  }
}

__global__ void prep_b(const float* __restrict__ bih0, const float* __restrict__ bhh0,
                       const float* __restrict__ bih1, const float* __restrict__ bhh1,
                       float* __restrict__ bias0, float* __restrict__ bias1) {
  int i = blockIdx.x * blockDim.x + threadIdx.x;
  if (i < HH) {
    bias0[i]        = bih0[i] + bhh0[i];
    bias0[512 + i]  = bih0[512 + i] + bhh0[512 + i];
    bias0[1024 + i] = bih0[1024 + i];
    bias0[1536 + i] = bhh0[1024 + i];
    bias1[i]        = bih1[i] + bhh1[i];
    bias1[512 + i]  = bih1[512 + i] + bhh1[512 + i];
    bias1[1024 + i] = bih1[1024 + i];
    bias1[1536 + i] = bhh1[1024 + i];
  }
}

// 64 WGs x 256 threads, 4 roles x 16 WGs; each WG = 4 waves, one per 16-row batch
// group. NCOL=32: each WG owns 32 output cols (two MFMA col-tiles) -> the per-step
// all-to-all is over 16 producers instead of 32 (smaller E[max] detect tail, half
// the poll population). Weights in 123KB dynamic LDS. h1/h2 are WRITE-ONCE
// sequences (plain cached consumer loads); xp rings stay sc1.
__global__ __launch_bounds__(256, 1) void gru_persistent(
    const _Float16* __restrict__ x0,
    const float* __restrict__ Wih0, const float* __restrict__ Whh0,
    const float* __restrict__ Wih1, const float* __restrict__ Whh1,
    const float* __restrict__ bias0, const float* __restrict__ bias1,
    _Float16* h1seq, _Float16* h2seq, float* xp0ring, float* xp1ring,
    float* pooled, int* flags0, int* flagsP0, int* flagsP1, int* flags1)
{
  extern __shared__ _Float16 wlds[];  // 16 chunks x 3840 halves + tile @61440
  const int wg   = blockIdx.x;
  const int role = wg >> 4;          // 0=L0 1=P0 2=P1 3=L1
  const int w    = wg & 15;          // column slice 0..15
  const int jb   = w * NCOL;         // 32 h-cols per WG
  const int tid  = threadIdx.x;
  const int g    = tid >> 6;         // wave = batch group, rows g*16..+15
  const int lane = tid & 63;
  const int quad = lane >> 4;
  const int l15  = lane & 15;
  const int kq   = quad * 8;
  const int hoff = (g * 16 + l15) * 1024 + quad * 16;  // byte voffset into an h slot

  // ---- one-time LDS weight fill (fp32 global -> f16, 40-half jj stride) ----
  {
    const float* Wsrc = (role == 0) ? Whh0 : (role == 1) ? Wih0
                      : (role == 2) ? Wih1 : Whh1;
    const int nch  = (role == 1) ? 10 : 16;
    const int Ksrc = (role == 1) ? EE : HH;
    for (int idx = tid; idx < nch * 384; idx += 256) {
      int q = idx & 3, jj = (idx >> 2) & 31, g3 = (idx >> 7) % 3, ch = idx / 384;
      int row = g3 * 512 + jb + jj;
      _Float16* dst = wlds + ch * CHH + g3 * GST + jj * 40 + q * 8;
      int colb = ch * 32 + q * 8;
      #pragma unroll
      for (int e = 0; e < 8; ++e) {
        int col = colb + e;
        dst[e] = (col < Ksrc) ? (_Float16)Wsrc[(size_t)row * Ksrc + col] : (_Float16)0.f;
      }
    }
  }
  __syncthreads();

  _Float16* tc = wlds + 16 * CHH + g * 512;   // per-wave [16][32] publish tile

  // xp static voffs: layout [row 64][c15 16][cs 32][16B f32 r,z,n,pad]; a lane's two
  // column-sets (cs=2w, 2w+1) are 32B-contiguous -> base voff + offset:0/16.
  int vx[4];
  #pragma unroll
  for (int rg = 0; rg < 4; ++rg)
    vx[rg] = (g * 16 + quad * 4 + rg) * 8192 + l15 * 512 + (2 * w) * 16;

  const int* fg0  = flags0  + g * 16 * FS;   // 16 producers x 64B per group
  const int* fgP0 = flagsP0 + g * 16 * FS;
  const int* fgP1 = flagsP1 + g * 16 * FS;
  const int* fg1  = flags1  + g * 16 * FS;

  if (role == 0) {            // ---------------- L0: h1 recurrence ----------------
    const int j0 = jb + l15, j1 = j0 + 16;
    const float br0 = bias0[j0], bz0 = bias0[512 + j0];
    const float bnx0 = bias0[1024 + j0], bnh0 = bias0[1536 + j0];
    const float br1 = bias0[j1], bz1 = bias0[512 + j1];
    const float bnx1 = bias0[1024 + j1], bnh1 = bias0[1536 + j1];
    int* myf = flags0 + (g * 16 + w) * FS;
    float hp0[4] = {0.f,0.f,0.f,0.f}, hp1[4] = {0.f,0.f,0.f,0.f};
    for (int s = 0; s < T_STEPS; ++s) {
      // own-group recurrence (16 producers); xp0[s] ready (P0 runs ahead)
      wave_wait16(fg0, s, fgP0, s + 1, fg0, s);
      f32x4 hR0 = {0.f,0.f,0.f,0.f}, hZ0 = {0.f,0.f,0.f,0.f}, hN0 = {0.f,0.f,0.f,0.f};
      f32x4 hR1 = {0.f,0.f,0.f,0.f}, hZ1 = {0.f,0.f,0.f,0.f}, hN1 = {0.f,0.f,0.f,0.f};
      f32x4 xp[8];
      const void* xb = (const char*)xp0ring + (size_t)(s & 15) * XPSLOT;
      if (s >= 1) {
        HMat hA;
        load_h_xp8(hA, xp, h1seq + (size_t)(s - 1) * HB, hoff, xb, vx);
        #pragma unroll 4
        for (int c = 0; c < 16; ++c) {
          f16x8 a = fragq(hA.q[c]);
          B3 b0 = ldsB(wlds, c, l15, kq);
          B3 b1 = ldsB(wlds, c, l15 + 16, kq);
          hR0 = mf(a, b0.r, hR0); hZ0 = mf(a, b0.z, hZ0); hN0 = mf(a, b0.n, hN0);
          hR1 = mf(a, b1.r, hR1); hZ1 = mf(a, b1.z, hZ1); hN1 = mf(a, b1.n, hN1);
        }
      } else {
        load_xp8(xp, xb, vx);
      }
      #pragma unroll
      for (int rg = 0; rg < 4; ++rg) {
        {
          f32x4 xv = xp[rg * 2];
          float r = sigf(xv[0] + hR0[rg] + br0);
          float z = sigf(xv[1] + hZ0[rg] + bz0);
          float n = tanhf(xv[2] + bnx0 + r * (hN0[rg] + bnh0));
          float hnew = (1.f - z) * n + z * hp0[rg];
          hp0[rg] = hnew;
          tc[(quad * 4 + rg) * 32 + l15] = (_Float16)hnew;
        }
        {
          f32x4 xv = xp[rg * 2 + 1];
          float r = sigf(xv[0] + hR1[rg] + br1);
          float z = sigf(xv[1] + hZ1[rg] + bz1);
          float n = tanhf(xv[2] + bnx1 + r * (hN1[rg] + bnh1));
          float hnew = (1.f - z) * n + z * hp1[rg];
          hp1[rg] = hnew;
          tc[(quad * 4 + rg) * 32 + 16 + l15] = (_Float16)hnew;
        }
      }
      {                                        // publish 16 rows x 64B (all 64 lanes)
        int row = lane >> 2, seg = lane & 3;
        f16x8 v = *(const f16x8*)&tc[row * 32 + seg * 8];
        st16_mall(h1seq + (size_t)s * HB
                  + (size_t)(g * 16 + row) * HH + jb + seg * 8, v);
      }
      __builtin_amdgcn_s_waitcnt(0);
      if (lane == 0) st4_dev(myf, s + 1);
    }
  } else if (role == 1) {     // ---------------- P0: x projection (ahead) ----------------
    int* myf = flagsP0 + (g * 16 + w) * FS;
    const int xoff = (g * 16 + l15) * 640 + quad * 16;
    for (int t = 0; t < T_STEPS; ++t) {
      wave_wait16(fg0, t - 15, fg0, t - 15, fg0, t - 15);   // xp0 ring throttle only
      i32x4 xq[10];
      loadx10_wait(xq, x0 + (size_t)t * BB * EP, xoff);
      f32x4 aR0 = {0.f,0.f,0.f,0.f}, aZ0 = {0.f,0.f,0.f,0.f}, aN0 = {0.f,0.f,0.f,0.f};
      f32x4 aR1 = {0.f,0.f,0.f,0.f}, aZ1 = {0.f,0.f,0.f,0.f}, aN1 = {0.f,0.f,0.f,0.f};
      #pragma unroll 5
      for (int c = 0; c < 10; ++c) {
        f16x8 a = fragq(xq[c]);
        B3 b0 = ldsB(wlds, c, l15, kq);
        B3 b1 = ldsB(wlds, c, l15 + 16, kq);
        aR0 = mf(a, b0.r, aR0); aZ0 = mf(a, b0.z, aZ0); aN0 = mf(a, b0.n, aN0);
        aR1 = mf(a, b1.r, aR1); aZ1 = mf(a, b1.z, aZ1); aN1 = mf(a, b1.n, aN1);
      }
      char* xb = (char*)xp0ring + (size_t)(t & 15) * XPSLOT;
      #pragma unroll
      for (int rg = 0; rg < 4; ++rg) {
        f32x4 v0 = {aR0[rg], aZ0[rg], aN0[rg], 0.f};
        st16f(xb + vx[rg], v0);
        f32x4 v1 = {aR1[rg], aZ1[rg], aN1[rg], 0.f};
        st16f(xb + vx[rg] + 16, v1);
      }
      __builtin_amdgcn_s_waitcnt(0);
      if (lane == 0) st4_dev(myf, t + 1);
    }
  } else if (role == 2) {     // ---------------- P1: h1 -> xp1 projection ----------------
    int* myf = flagsP1 + (g * 16 + w) * FS;
    for (int t = 0; t < T_STEPS; ++t) {
      wave_wait16(fg0, t + 1, fg1, t - 3, fg0, t + 1);  // h1[t] ready; xp1 throttle
      HMat A;
      load16_plain(A, h1seq + (size_t)t * HB, hoff);
      f32x4 aR0 = {0.f,0.f,0.f,0.f}, aZ0 = {0.f,0.f,0.f,0.f}, aN0 = {0.f,0.f,0.f,0.f};
      f32x4 aR1 = {0.f,0.f,0.f,0.f}, aZ1 = {0.f,0.f,0.f,0.f}, aN1 = {0.f,0.f,0.f,0.f};
      #pragma unroll 4
      for (int c = 0; c < 16; ++c) {
        f16x8 a = fragq(A.q[c]);
        B3 b0 = ldsB(wlds, c, l15, kq);
        B3 b1 = ldsB(wlds, c, l15 + 16, kq);
        aR0 = mf(a, b0.r, aR0); aZ0 = mf(a, b0.z, aZ0); aN0 = mf(a, b0.n, aN0);
        aR1 = mf(a, b1.r, aR1); aZ1 = mf(a, b1.z, aZ1); aN1 = mf(a, b1.n, aN1);
      }
      char* xb = (char*)xp1ring + (size_t)(t & 3) * XPSLOT;
      #pragma unroll
      for (int rg = 0; rg < 4; ++rg) {
        f32x4 v0 = {aR0[rg], aZ0[rg], aN0[rg], 0.f};
        st16f(xb + vx[rg], v0);
        f32x4 v1 = {aR1[rg], aZ1[rg], aN1[rg], 0.f};
        st16f(xb + vx[rg] + 16, v1);
      }
      __builtin_amdgcn_s_waitcnt(0);
      if (lane == 0) st4_dev(myf, t + 1);
    }
  } else {                    // ---------------- L1: h2 recurrence ----------------
    const int j0 = jb + l15, j1 = j0 + 16;
    const float br0 = bias1[j0], bz0 = bias1[512 + j0];
    const float bnx0 = bias1[1024 + j0], bnh0 = bias1[1536 + j0];
    const float br1 = bias1[j1], bz1 = bias1[512 + j1];
    const float bnx1 = bias1[1024 + j1], bnh1 = bias1[1536 + j1];
    int* myf = flags1 + (g * 16 + w) * FS;
    float hp0[4] = {0.f,0.f,0.f,0.f}, hp1[4] = {0.f,0.f,0.f,0.f};
    for (int t = 0; t < T_STEPS; ++t) {
      wave_wait16(fg1, t, fgP1, t + 1, fg1, t);  // own recurrence; xp1[t] ready
      f32x4 hR0 = {0.f,0.f,0.f,0.f}, hZ0 = {0.f,0.f,0.f,0.f}, hN0 = {0.f,0.f,0.f,0.f};
      f32x4 hR1 = {0.f,0.f,0.f,0.f}, hZ1 = {0.f,0.f,0.f,0.f}, hN1 = {0.f,0.f,0.f,0.f};
      f32x4 xp[8];
      const void* xb = (const char*)xp1ring + (size_t)(t & 3) * XPSLOT;
      if (t >= 1) {
        HMat hA;
        load_h_xp8(hA, xp, h2seq + (size_t)(t - 1) * HB, hoff, xb, vx);
        #pragma unroll 4
        for (int c = 0; c < 16; ++c) {
          f16x8 a = fragq(hA.q[c]);
          B3 b0 = ldsB(wlds, c, l15, kq);
          B3 b1 = ldsB(wlds, c, l15 + 16, kq);
          hR0 = mf(a, b0.r, hR0); hZ0 = mf(a, b0.z, hZ0); hN0 = mf(a, b0.n, hN0);
          hR1 = mf(a, b1.r, hR1); hZ1 = mf(a, b1.z, hZ1); hN1 = mf(a, b1.n, hN1);
        }
      } else {
        load_xp8(xp, xb, vx);
      }
      #pragma unroll
      for (int rg = 0; rg < 4; ++rg) {
        {
          f32x4 xv = xp[rg * 2];
          float r = sigf(xv[0] + hR0[rg] + br0);
          float z = sigf(xv[1] + hZ0[rg] + bz0);
          float n = tanhf(xv[2] + bnx0 + r * (hN0[rg] + bnh0));
          float hnew = (1.f - z) * n + z * hp0[rg];
          hp0[rg] = hnew;
          tc[(quad * 4 + rg) * 32 + l15] = (_Float16)hnew;
        }
        {
          f32x4 xv = xp[rg * 2 + 1];
          float r = sigf(xv[0] + hR1[rg] + br1);
          float z = sigf(xv[1] + hZ1[rg] + bz1);
          float n = tanhf(xv[2] + bnx1 + r * (hN1[rg] + bnh1));
          float hnew = (1.f - z) * n + z * hp1[rg];
          hp1[rg] = hnew;
          tc[(quad * 4 + rg) * 32 + 16 + l15] = (_Float16)hnew;
        }
      }
      {
        int row = lane >> 2, seg = lane & 3;
        f16x8 v = *(const f16x8*)&tc[row * 32 + seg * 8];
        st16_mall(h2seq + (size_t)t * HB
                  + (size_t)(g * 16 + row) * HH + jb + seg * 8, v);
      }
      __builtin_amdgcn_s_waitcnt(0);
      if (lane == 0) st4_dev(myf, t + 1);
      // tail (off the flag path): pooled partial sums, raw; /64 in FC
      if (lane < 32) {
        float sum = 0.f;
        #pragma unroll
        for (int r = 0; r < 16; ++r) sum += (float)tc[r * 32 + lane];
        atomicAdd(pooled + (size_t)t * HH + jb + lane, sum);
      }
    }
  }
}

__global__ void fc_kernel(const float* __restrict__ pooled, const float* __restrict__ fcW,
                          const float* __restrict__ fcb, float* __restrict__ out) {
  const int t = blockIdx.x;
  const int lane = threadIdx.x;  // 64 = one wave
  float a0 = 0.f, a1 = 0.f, a2 = 0.f, a3 = 0.f, a4 = 0.f;
  for (int jj = lane; jj < HH; jj += 64) {
    float p = pooled[(size_t)t * HH + jj];
    a0 += p * fcW[jj];
    a1 += p * fcW[512 + jj];
    a2 += p * fcW[1024 + jj];
    a3 += p * fcW[1536 + jj];
    a4 += p * fcW[2048 + jj];
  }
  #pragma unroll
  for (int off = 32; off > 0; off >>= 1) {
    a0 += __shfl_down(a0, off, 64);
    a1 += __shfl_down(a1, off, 64);
    a2 += __shfl_down(a2, off, 64);
    a3 += __shfl_down(a3, off, 64);
    a4 += __shfl_down(a4, off, 64);
  }
  if (lane == 0) {
    const float sc = 1.f / 64.f;
    out[t * 5 + 0] = a0 * sc + fcb[0];
    out[t * 5 + 1] = a1 * sc + fcb[1];
    out[t * 5 + 2] = a2 * sc + fcb[2];
    out[t * 5 + 3] = a3 * sc + fcb[3];
    out[t * 5 + 4] = a4 * sc + fcb[4];
  }
}

extern "C" void kernel_launch(void* const* d_in, const int* in_sizes, int n_in,
                              void* d_out, int out_size, void* d_ws, size_t ws_size,
                              hipStream_t stream) {
  const int*   texts = (const int*)  d_in[0];
  const float* emb   = (const float*)d_in[1];
  const float* Wih0  = (const float*)d_in[2];
  const float* Whh0  = (const float*)d_in[3];
  const float* bih0  = (const float*)d_in[4];
  const float* bhh0  = (const float*)d_in[5];
  const float* Wih1  = (const float*)d_in[6];
  const float* Whh1  = (const float*)d_in[7];
  const float* bih1  = (const float*)d_in[8];
  const float* bhh1  = (const float*)d_in[9];
  const float* fcW   = (const float*)d_in[10];
  const float* fcb   = (const float*)d_in[11];
  float* out = (float*)d_out;

  char* ws = (char*)d_ws;
  int*      flags0  = (int*)ws;                      // 4096 B (4 grp x 16 x 64B)
  int*      flagsP0 = (int*)(ws + 8192);             // 4096 B
  int*      flagsP1 = (int*)(ws + 16384);            // 4096 B
  int*      flags1  = (int*)(ws + 24576);            // 4096 B
  float*    pooled  = (float*)(ws + 32768);          // 1048576 B [512][512] f32
  _Float16* h1seq   = (_Float16*)(ws + 1081344);     // 33554432 B (512 x 64KB, write-once)
  _Float16* h2seq   = (_Float16*)(ws + 34635776);    // 33554432 B (512 x 64KB, write-once)
  float*    xp1ring = (float*)(ws + 68190208);       // 2097152 B (4 x 512KB)
  float*    xp0ring = (float*)(ws + 70287360);       // 8388608 B (16 x 512KB)
  _Float16* x0      = (_Float16*)(ws + 78675968);    // 20971520 B [512][64][320]
  float*    bias0   = (float*)(ws + 99647488);       // 8192 B (r,z,nx,nh)
  float*    bias1   = (float*)(ws + 99655680);       // 8192 B
  // total ws use: 99663872 B

  hipFuncSetAttribute((const void*)gru_persistent,
                      hipFuncAttributeMaxDynamicSharedMemorySize, DYNLDS);

  hipMemsetAsync(ws, 0, 1081344, stream);  // flags + pooled = zeros
  prep_x0<<<4096, 256, 0, stream>>>(texts, emb, x0);
  prep_b<<<2, 256, 0, stream>>>(bih0, bhh0, bih1, bhh1, bias0, bias1);
  gru_persistent<<<64, 256, DYNLDS, stream>>>(x0, Wih0, Whh0, Wih1, Whh1, bias0, bias1,
                                              h1seq, h2seq, xp0ring, xp1ring, pooled,
                                              flags0, flagsP0, flagsP1, flags1);
  fc_kernel<<<512, 64, 0, stream>>>(pooled, fcW, fcb, out);
}

// Round 9
// 4359.705 us; speedup vs baseline: 1.3175x; 1.3175x over previous
//
#include <hip/hip_runtime.h>

#define T_STEPS 512
#define BB 64
#define EE 300
#define EP 320
#define HH 512
#define HB (BB*HH)        // halves per h slot (65536 B)
#define XPSLOT 524288     // bytes per xp slot: 64 rows * 512 cols * 16B (f32 r,z,n,pad)
#define FS 16             // flag stride in ints (64 B): producer-exclusive cache line

typedef _Float16 f16x8 __attribute__((ext_vector_type(8)));
typedef float f32x4 __attribute__((ext_vector_type(4)));
typedef int i32x4 __attribute__((ext_vector_type(4)));

__device__ __forceinline__ f32x4 mf(f16x8 a, f16x8 b, f32x4 c) {
  return __builtin_amdgcn_mfma_f32_16x16x32_f16(a, b, c, 0, 0, 0);
}

struct HMat { i32x4 q[16]; };   // 64 VGPRs: one lane's 16 A-fragments of a 16-row tile

// 16 back-to-back PLAIN (L2-cached) 16B loads + FULL drain in ONE asm block.
// h slots are WRITE-ONCE per dispatch: first reader on an XCD fills L2 from MALL,
// the other consumer WGs on that XCD hit L2 (~8x less MALL read traffic).
#define LOADS16_PLAIN                                                \
    "global_load_dwordx4 %0,  %16, %17\n\t"                          \
    "global_load_dwordx4 %1,  %16, %17 offset:64\n\t"                \
    "global_load_dwordx4 %2,  %16, %17 offset:128\n\t"               \
    "global_load_dwordx4 %3,  %16, %17 offset:192\n\t"               \
    "global_load_dwordx4 %4,  %16, %17 offset:256\n\t"               \
    "global_load_dwordx4 %5,  %16, %17 offset:320\n\t"               \
    "global_load_dwordx4 %6,  %16, %17 offset:384\n\t"               \
    "global_load_dwordx4 %7,  %16, %17 offset:448\n\t"               \
    "global_load_dwordx4 %8,  %16, %17 offset:512\n\t"               \
    "global_load_dwordx4 %9,  %16, %17 offset:576\n\t"               \
    "global_load_dwordx4 %10, %16, %17 offset:640\n\t"               \
    "global_load_dwordx4 %11, %16, %17 offset:704\n\t"               \
    "global_load_dwordx4 %12, %16, %17 offset:768\n\t"               \
    "global_load_dwordx4 %13, %16, %17 offset:832\n\t"               \
    "global_load_dwordx4 %14, %16, %17 offset:896\n\t"               \
    "global_load_dwordx4 %15, %16, %17 offset:960\n\t"               \
    "s_waitcnt vmcnt(0)"

#define HM_OUTS(m) "=v"((m).q[0]), "=v"((m).q[1]), "=v"((m).q[2]), "=v"((m).q[3]),   \
                   "=v"((m).q[4]), "=v"((m).q[5]), "=v"((m).q[6]), "=v"((m).q[7]),   \
                   "=v"((m).q[8]), "=v"((m).q[9]), "=v"((m).q[10]), "=v"((m).q[11]), \
                   "=v"((m).q[12]), "=v"((m).q[13]), "=v"((m).q[14]), "=v"((m).q[15])

__device__ __forceinline__ void load16_plain(HMat& m, const void* base, int voff) {
  asm volatile(LOADS16_PLAIN : HM_OUTS(m) : "v"(voff), "s"(base) : "memory");
}

// fused: 16 PLAIN h-loads (write-once buffer) + 4 sc1 xp loads (reused ring — MUST
// bypass L2 or a stale line from 16 steps ago could be served), ONE drain.
#define LOADS16_XP4_MIX                                              \
    "global_load_dwordx4 %0,  %20, %21\n\t"                          \
    "global_load_dwordx4 %1,  %20, %21 offset:64\n\t"                \
    "global_load_dwordx4 %2,  %20, %21 offset:128\n\t"               \
    "global_load_dwordx4 %3,  %20, %21 offset:192\n\t"               \
    "global_load_dwordx4 %4,  %20, %21 offset:256\n\t"               \
    "global_load_dwordx4 %5,  %20, %21 offset:320\n\t"               \
    "global_load_dwordx4 %6,  %20, %21 offset:384\n\t"               \
    "global_load_dwordx4 %7,  %20, %21 offset:448\n\t"               \
    "global_load_dwordx4 %8,  %20, %21 offset:512\n\t"               \
    "global_load_dwordx4 %9,  %20, %21 offset:576\n\t"               \
    "global_load_dwordx4 %10, %20, %21 offset:640\n\t"               \
    "global_load_dwordx4 %11, %20, %21 offset:704\n\t"               \
    "global_load_dwordx4 %12, %20, %21 offset:768\n\t"               \
    "global_load_dwordx4 %13, %20, %21 offset:832\n\t"               \
    "global_load_dwordx4 %14, %20, %21 offset:896\n\t"               \
    "global_load_dwordx4 %15, %20, %21 offset:960\n\t"               \
    "global_load_dwordx4 %16, %22, %26 sc1\n\t"                      \
    "global_load_dwordx4 %17, %23, %26 sc1\n\t"                      \
    "global_load_dwordx4 %18, %24, %26 sc1\n\t"                      \
    "global_load_dwordx4 %19, %25, %26 sc1\n\t"                      \
    "s_waitcnt vmcnt(0)"

__device__ __forceinline__ void load_h_xp(HMat& m, f32x4* xp,
                                          const void* hbase, int hvoff,
                                          const void* xbase, const int* vx) {
  asm volatile(LOADS16_XP4_MIX
    : HM_OUTS(m), "=v"(xp[0]), "=v"(xp[1]), "=v"(xp[2]), "=v"(xp[3])
    : "v"(hvoff), "s"(hbase), "v"(vx[0]), "v"(vx[1]), "v"(vx[2]), "v"(vx[3]), "s"(xbase)
    : "memory");
}

__device__ __forceinline__ void load_xp4(f32x4* xp, const void* xbase, const int* vx) {
  asm volatile(
    "global_load_dwordx4 %0, %4, %8 sc1\n\t"
    "global_load_dwordx4 %1, %5, %8 sc1\n\t"
    "global_load_dwordx4 %2, %6, %8 sc1\n\t"
    "global_load_dwordx4 %3, %7, %8 sc1\n\t"
    "s_waitcnt vmcnt(0)"
    : "=v"(xp[0]), "=v"(xp[1]), "=v"(xp[2]), "=v"(xp[3])
    : "v"(vx[0]), "v"(vx[1]), "v"(vx[2]), "v"(vx[3]), "s"(xbase) : "memory");
}

// batched x-prefetch: 10 plain cached loads + full drain (x0 is immutable)
__device__ __forceinline__ void loadx10_wait(i32x4* xq, const void* base, int voff) {
  asm volatile(
    "global_load_dwordx4 %0, %10, %11\n\t"
    "global_load_dwordx4 %1, %10, %11 offset:64\n\t"
    "global_load_dwordx4 %2, %10, %11 offset:128\n\t"
    "global_load_dwordx4 %3, %10, %11 offset:192\n\t"
    "global_load_dwordx4 %4, %10, %11 offset:256\n\t"
    "global_load_dwordx4 %5, %10, %11 offset:320\n\t"
    "global_load_dwordx4 %6, %10, %11 offset:384\n\t"
    "global_load_dwordx4 %7, %10, %11 offset:448\n\t"
    "global_load_dwordx4 %8, %10, %11 offset:512\n\t"
    "global_load_dwordx4 %9, %10, %11 offset:576\n\t"
    "s_waitcnt vmcnt(0)"
    : "=v"(xq[0]), "=v"(xq[1]), "=v"(xq[2]), "=v"(xq[3]), "=v"(xq[4]),
      "=v"(xq[5]), "=v"(xq[6]), "=v"(xq[7]), "=v"(xq[8]), "=v"(xq[9])
    : "v"(voff), "s"(base) : "memory");
}

__device__ __forceinline__ f16x8 fragq(i32x4 q) {
  union { i32x4 i; f16x8 v; } x; x.i = q; return x.v;
}

// publish: write-through to MALL (no L2 allocate) so consumers' L2 fills are fresh
__device__ __forceinline__ void st16_mall(void* p, f16x8 v) {
  i32x4 iv;
  __builtin_memcpy(&iv, &v, 16);
  asm volatile("global_store_dwordx4 %0, %1, off sc0 sc1" :: "v"(p), "v"(iv) : "memory");
}
__device__ __forceinline__ void st16f(void* p, f32x4 v) {
  i32x4 iv;
  __builtin_memcpy(&iv, &v, 16);
  asm volatile("global_store_dwordx4 %0, %1, off sc0 sc1" :: "v"(p), "v"(iv) : "memory");
}
__device__ __forceinline__ void st4_dev(int* p, int v) {
  asm volatile("global_store_dword %0, %1, off sc0 sc1" :: "v"(p), "v"(v) : "memory");
}

// per-WAVE joint poll, R7's proven layout: producer-exclusive 64B flag lines.
// lanes 0-31 poll pa[lane*FS]>=ta, lanes 32-63 poll pb[(lane-32)*FS]>=tb; ALL lanes
// also poll pc[(lane&31)*FS]>=tc_. Targets <=0 pass trivially (flags monotone >=0).
// slp: sampling backoff — 1 (64cy) on critical-path waits, 8 on slack throttles
// (reduces background MALL poll traffic without adding detect tail where it counts).
__device__ __forceinline__ void wave_wait(const int* pa, int ta,
                                          const int* pb, int tb,
                                          const int* pc, int tc_, int slp) {
  const int lane = threadIdx.x & 63;
  const int* p1 = (lane < 32) ? (pa + lane * FS) : (pb + (lane - 32) * FS);
  const int t1 = (lane < 32) ? ta : tb;
  const int* p2 = pc + (lane & 31) * FS;
  for (;;) {
    int v1, v2;
    asm volatile(
      "global_load_dword %0, %2, off sc1\n\t"
      "global_load_dword %1, %3, off sc1\n\t"
      "s_waitcnt vmcnt(0)"
      : "=v"(v1), "=v"(v2) : "v"(p1), "v"(p2) : "memory");
    if (__all((v1 >= t1) && (v2 >= tc_))) return;
    for (int i = 0; i < slp; ++i) __builtin_amdgcn_s_sleep(1);
  }
}

__device__ __forceinline__ float sigf(float x) { return 1.f / (1.f + __expf(-x)); }

struct B3 { f16x8 r, z, n; };
// LDS weight read: [chunk][gate(3)][jj(16)][40 halves] — 40-half jj stride spreads the
// 16 cols across bank windows 4*((5*jj+quad) mod 8): uniform, max 2-way (free).
__device__ __forceinline__ B3 ldsB(const _Float16* wl, int chunk, int jj, int kq) {
  B3 o;
  const _Float16* p = wl + chunk * 1920 + jj * 40 + kq;
  o.r = *(const f16x8*)p;
  o.z = *(const f16x8*)(p + 640);
  o.n = *(const f16x8*)(p + 1280);
  return o;
}

__global__ void prep_x0(const int* __restrict__ texts, const float* __restrict__ emb,
                        _Float16* __restrict__ x0) {
  const size_t N = (size_t)T_STEPS * BB * EP;
  const size_t stride = (size_t)gridDim.x * blockDim.x;
  for (size_t i = (size_t)blockIdx.x * blockDim.x + threadIdx.x; i < N; i += stride) {
    int e = (int)(i % EP);
    size_t tb = i / EP;
    float v = 0.f;
    if (e < EE) v = emb[(size_t)texts[tb] * EE + e];
    x0[i] = (_Float16)v;
  }
}

__global__ void prep_b(const float* __restrict__ bih0, const float* __restrict__ bhh0,
                       const float* __restrict__ bih1, const float* __restrict__ bhh1,
                       float* __restrict__ bias0, float* __restrict__ bias1) {
  int i = blockIdx.x * blockDim.x + threadIdx.x;
  if (i < HH) {
    bias0[i]        = bih0[i] + bhh0[i];
    bias0[512 + i]  = bih0[512 + i] + bhh0[512 + i];
    bias0[1024 + i] = bih0[1024 + i];
    bias0[1536 + i] = bhh0[1024 + i];
    bias1[i]        = bih1[i] + bhh1[i];
    bias1[512 + i]  = bih1[512 + i] + bhh1[512 + i];
    bias1[1024 + i] = bih1[1024 + i];
    bias1[1536 + i] = bhh1[1024 + i];
  }
}

// 128 WGs x 256 threads, 4 roles x 32 WGs; each WG = 4 independent waves, one per
// 16-row batch group (GRU rows are independent -> 8 decoupled pipelines).
//   role 0 (L0): h1 recurrence, Whh0 in LDS, consumes precomputed xp0 (f32).
//   role 1 (P0): x0 @ Wih0^T -> xp0 ring (16 slots), runs ~15 steps ahead (off path).
//   role 2 (P1): h1 @ Wih1^T -> xp1 ring (4 slots), pipelined between L0 and L1.
//   role 3 (L1): h2 recurrence, Whh1 in LDS, consumes xp1; pooled atomics in tail.
// h1/h2 are WRITE-ONCE sequences (512 x 64KB): consumers use plain cached loads
// (L2 read amplification); no h-ring throttles needed. xp rings stay sc1.
__global__ __launch_bounds__(256, 1) void gru_persistent(
    const _Float16* __restrict__ x0,
    const float* __restrict__ Wih0, const float* __restrict__ Whh0,
    const float* __restrict__ Wih1, const float* __restrict__ Whh1,
    const float* __restrict__ bias0, const float* __restrict__ bias1,
    _Float16* h1seq, _Float16* h2seq, float* xp0ring, float* xp1ring,
    float* pooled, int* flags0, int* flagsP0, int* flagsP1, int* flags1)
{
  const int wg   = blockIdx.x;
  const int role = wg >> 5;          // 0=L0 1=P0 2=P1 3=L1
  const int w    = wg & 31;          // column slice 0..31
  const int jb   = w * 16;           // 16 h-cols per WG
  const int tid  = threadIdx.x;
  const int g    = tid >> 6;         // wave = batch group, rows g*16..+15
  const int lane = tid & 63;
  const int quad = lane >> 4;
  const int l15  = lane & 15;
  const int kq   = quad * 8;
  const int hoff = (g * 16 + l15) * 1024 + quad * 16;  // byte voffset into an h slot

  __shared__ alignas(16) _Float16 wlds[30720];     // 16 chunks x 1920 halves = 60 KiB
  __shared__ alignas(16) _Float16 tile[4][16][16]; // per-wave publish transpose, 2 KiB

  // ---- one-time LDS weight fill (fp32 global -> f16, 40-half jj stride) ----
  {
    const float* Wsrc = (role == 0) ? Whh0 : (role == 1) ? Wih0
                      : (role == 2) ? Wih1 : Whh1;
    const int nch  = (role == 1) ? 10 : 16;
    const int Ksrc = (role == 1) ? EE : HH;
    for (int idx = tid; idx < nch * 192; idx += 256) {
      int q = idx & 3, jj = (idx >> 2) & 15, g3 = (idx >> 6) % 3, ch = idx / 192;
      int row = g3 * 512 + jb + jj;
      _Float16* dst = wlds + ch * 1920 + g3 * 640 + jj * 40 + q * 8;
      int colb = ch * 32 + q * 8;
      #pragma unroll
      for (int e = 0; e < 8; ++e) {
        int col = colb + e;
        dst[e] = (col < Ksrc) ? (_Float16)Wsrc[(size_t)row * Ksrc + col] : (_Float16)0.f;
      }
    }
  }
  __syncthreads();

  // loop-invariant xp voffsets: [row 64][hcol 512][gate pad4] f32 -> row stride 8192 B
  int vx[4];
  #pragma unroll
  for (int rg = 0; rg < 4; ++rg)
    vx[rg] = (g * 16 + quad * 4 + rg) * 8192 + (jb + l15) * 16;

  const int* fg0  = flags0  + g * 32 * FS;   // 32 producers x 64B per group
  const int* fgP0 = flagsP0 + g * 32 * FS;
  const int* fgP1 = flagsP1 + g * 32 * FS;
  const int* fg1  = flags1  + g * 32 * FS;

  if (role == 0) {            // ---------------- L0: h1 recurrence ----------------
    const int j = jb + l15;
    const float br = bias0[j], bz = bias0[512 + j];
    const float bnx = bias0[1024 + j], bnh = bias0[1536 + j];
    int* myf = flags0 + (g * 32 + w) * FS;
    float hprev[4] = {0.f, 0.f, 0.f, 0.f};
    _Float16 (*tc)[16] = tile[g];
    for (int s = 0; s < T_STEPS; ++s) {
      // own-group recurrence; xp0[s] ready (P0 runs ahead). CRITICAL: fast sampling.
      wave_wait(fg0, s, fg0, s, fgP0, s + 1, 1);
      f32x4 hR = {0.f,0.f,0.f,0.f}, hZ = {0.f,0.f,0.f,0.f}, hN = {0.f,0.f,0.f,0.f};
      f32x4 xp[4];
      const void* xb = (const char*)xp0ring + (size_t)(s & 15) * XPSLOT;
      if (s >= 1) {
        HMat hA;
        load_h_xp(hA, xp, h1seq + (size_t)(s - 1) * HB, hoff, xb, vx);
        #pragma unroll 4
        for (int c = 0; c < 16; ++c) {
          f16x8 a = fragq(hA.q[c]);
          B3 bb = ldsB(wlds, c, l15, kq);
          hR = mf(a, bb.r, hR); hZ = mf(a, bb.z, hZ); hN = mf(a, bb.n, hN);
        }
      } else {
        load_xp4(xp, xb, vx);
      }
      #pragma unroll
      for (int rg = 0; rg < 4; ++rg) {
        float r = sigf(xp[rg][0] + hR[rg] + br);
        float z = sigf(xp[rg][1] + hZ[rg] + bz);
        float n = tanhf(xp[rg][2] + bnx + r * (hN[rg] + bnh));
        float hnew = (1.f - z) * n + z * hprev[rg];
        hprev[rg] = hnew;
        tc[quad * 4 + rg][l15] = (_Float16)hnew;
      }
      if (lane < 32) {                      // 16 rows x 32B per wave
        int row = lane & 15, hb = lane >> 4;
        f16x8 v = *(const f16x8*)&tc[row][hb * 8];
        st16_mall(h1seq + (size_t)s * HB
                  + (size_t)(g * 16 + row) * HH + jb + hb * 8, v);
      }
      __builtin_amdgcn_s_waitcnt(0);
      if (lane == 0) st4_dev(myf, s + 1);
    }
  } else if (role == 1) {     // ---------------- P0: x projection (ahead) ----------------
    int* myf = flagsP0 + (g * 32 + w) * FS;
    const int xoff = (g * 16 + l15) * 640 + quad * 16;
    for (int t = 0; t < T_STEPS; ++t) {
      // xp0 ring throttle only — SLACK: slow sampling cuts background poll traffic
      wave_wait(fg0, t - 15, fg0, t - 15, fg0, t - 15, 8);
      i32x4 xq[10];
      loadx10_wait(xq, x0 + (size_t)t * BB * EP, xoff);
      f32x4 aR = {0.f,0.f,0.f,0.f}, aZ = {0.f,0.f,0.f,0.f}, aN = {0.f,0.f,0.f,0.f};
      #pragma unroll 5
      for (int c = 0; c < 10; ++c) {
        f16x8 a = fragq(xq[c]);
        B3 bb = ldsB(wlds, c, l15, kq);
        aR = mf(a, bb.r, aR); aZ = mf(a, bb.z, aZ); aN = mf(a, bb.n, aN);
      }
      char* xb = (char*)xp0ring + (size_t)(t & 15) * XPSLOT;
      #pragma unroll
      for (int rg = 0; rg < 4; ++rg) {
        f32x4 v = {aR[rg], aZ[rg], aN[rg], 0.f};
        st16f(xb + vx[rg], v);
      }
      __builtin_amdgcn_s_waitcnt(0);
      if (lane == 0) st4_dev(myf, t + 1);
    }
  } else if (role == 2) {     // ---------------- P1: h1 -> xp1 projection ----------------
    int* myf = flagsP1 + (g * 32 + w) * FS;
    for (int t = 0; t < T_STEPS; ++t) {
      // h1[t] ready (critical hop L0->L1); xp1 ring throttle
      wave_wait(fg0, t + 1, fg1, t - 3, fg0, t + 1, 1);
      HMat A;
      load16_plain(A, h1seq + (size_t)t * HB, hoff);
      f32x4 aR = {0.f,0.f,0.f,0.f}, aZ = {0.f,0.f,0.f,0.f}, aN = {0.f,0.f,0.f,0.f};
      #pragma unroll 4
      for (int c = 0; c < 16; ++c) {
        f16x8 a = fragq(A.q[c]);
        B3 bb = ldsB(wlds, c, l15, kq);
        aR = mf(a, bb.r, aR); aZ = mf(a, bb.z, aZ); aN = mf(a, bb.n, aN);
      }
      char* xb = (char*)xp1ring + (size_t)(t & 3) * XPSLOT;
      #pragma unroll
      for (int rg = 0; rg < 4; ++rg) {
        f32x4 v = {aR[rg], aZ[rg], aN[rg], 0.f};
        st16f(xb + vx[rg], v);
      }
      __builtin_amdgcn_s_waitcnt(0);
      if (lane == 0) st4_dev(myf, t + 1);
    }
  } else {                    // ---------------- L1: h2 recurrence ----------------
    const int j = jb + l15;
    const float br = bias1[j], bz = bias1[512 + j];
    const float bnx = bias1[1024 + j], bnh = bias1[1536 + j];
    int* myf = flags1 + (g * 32 + w) * FS;
    float hprev[4] = {0.f, 0.f, 0.f, 0.f};
    _Float16 (*tc)[16] = tile[g];
    for (int t = 0; t < T_STEPS; ++t) {
      // own recurrence; xp1[t] ready. CRITICAL: fast sampling.
      wave_wait(fg1, t, fgP1, t + 1, fg1, t, 1);
      f32x4 hR = {0.f,0.f,0.f,0.f}, hZ = {0.f,0.f,0.f,0.f}, hN = {0.f,0.f,0.f,0.f};
      f32x4 xp[4];
      const void* xb = (const char*)xp1ring + (size_t)(t & 3) * XPSLOT;
      if (t >= 1) {
        HMat hA;
        load_h_xp(hA, xp, h2seq + (size_t)(t - 1) * HB, hoff, xb, vx);
        #pragma unroll 4
        for (int c = 0; c < 16; ++c) {
          f16x8 a = fragq(hA.q[c]);
          B3 bb = ldsB(wlds, c, l15, kq);
          hR = mf(a, bb.r, hR); hZ = mf(a, bb.z, hZ); hN = mf(a, bb.n, hN);
        }
      } else {
        load_xp4(xp, xb, vx);
      }
      #pragma unroll
      for (int rg = 0; rg < 4; ++rg) {
        float r = sigf(xp[rg][0] + hR[rg] + br);
        float z = sigf(xp[rg][1] + hZ[rg] + bz);
        float n = tanhf(xp[rg][2] + bnx + r * (hN[rg] + bnh));
        float hnew = (1.f - z) * n + z * hprev[rg];
        hprev[rg] = hnew;
        tc[quad * 4 + rg][l15] = (_Float16)hnew;
      }
      if (lane < 32) {
        int row = lane & 15, hb = lane >> 4;
        f16x8 v = *(const f16x8*)&tc[row][hb * 8];
        st16_mall(h2seq + (size_t)t * HB
                  + (size_t)(g * 16 + row) * HH + jb + hb * 8, v);
      }
      __builtin_amdgcn_s_waitcnt(0);
      if (lane == 0) st4_dev(myf, t + 1);
      // tail (off the flag path): pooled partial sums, raw; /64 in FC
      if (lane < 16) {
        float sum = 0.f;
        #pragma unroll
        for (int r = 0; r < 16; ++r) sum += (float)tc[r][lane];
        atomicAdd(pooled + (size_t)t * HH + jb + lane, sum);
      }
    }
  }
}

__global__ void fc_kernel(const float* __restrict__ pooled, const float* __restrict__ fcW,
                          const float* __restrict__ fcb, float* __restrict__ out) {
  const int t = blockIdx.x;
  const int lane = threadIdx.x;  // 64 = one wave
  float a0 = 0.f, a1 = 0.f, a2 = 0.f, a3 = 0.f, a4 = 0.f;
  for (int jj = lane; jj < HH; jj += 64) {
    float p = pooled[(size_t)t * HH + jj];
    a0 += p * fcW[jj];
    a1 += p * fcW[512 + jj];
    a2 += p * fcW[1024 + jj];
    a3 += p * fcW[1536 + jj];
    a4 += p * fcW[2048 + jj];
  }
  #pragma unroll
  for (int off = 32; off > 0; off >>= 1) {
    a0 += __shfl_down(a0, off, 64);
    a1 += __shfl_down(a1, off, 64);
    a2 += __shfl_down(a2, off, 64);
    a3 += __shfl_down(a3, off, 64);
    a4 += __shfl_down(a4, off, 64);
  }
  if (lane == 0) {
    const float sc = 1.f / 64.f;
    out[t * 5 + 0] = a0 * sc + fcb[0];
    out[t * 5 + 1] = a1 * sc + fcb[1];
    out[t * 5 + 2] = a2 * sc + fcb[2];
    out[t * 5 + 3] = a3 * sc + fcb[3];
    out[t * 5 + 4] = a4 * sc + fcb[4];
  }
}

extern "C" void kernel_launch(void* const* d_in, const int* in_sizes, int n_in,
                              void* d_out, int out_size, void* d_ws, size_t ws_size,
                              hipStream_t stream) {
  const int*   texts = (const int*)  d_in[0];
  const float* emb   = (const float*)d_in[1];
  const float* Wih0  = (const float*)d_in[2];
  const float* Whh0  = (const float*)d_in[3];
  const float* bih0  = (const float*)d_in[4];
  const float* bhh0  = (const float*)d_in[5];
  const float* Wih1  = (const float*)d_in[6];
  const float* Whh1  = (const float*)d_in[7];
  const float* bih1  = (const float*)d_in[8];
  const float* bhh1  = (const float*)d_in[9];
  const float* fcW   = (const float*)d_in[10];
  const float* fcb   = (const float*)d_in[11];
  float* out = (float*)d_out;

  char* ws = (char*)d_ws;
  int*      flags0  = (int*)ws;                      // 8192 B (4 grp x 32 x 64B)
  int*      flagsP0 = (int*)(ws + 8192);             // 8192 B
  int*      flagsP1 = (int*)(ws + 16384);            // 8192 B
  int*      flags1  = (int*)(ws + 24576);            // 8192 B
  float*    pooled  = (float*)(ws + 32768);          // 1048576 B [512][512] f32
  _Float16* h1seq   = (_Float16*)(ws + 1081344);     // 33554432 B (512 x 64KB, write-once)
  _Float16* h2seq   = (_Float16*)(ws + 34635776);    // 33554432 B (512 x 64KB, write-once)
  float*    xp1ring = (float*)(ws + 68190208);       // 2097152 B (4 x 512KB)
  float*    xp0ring = (float*)(ws + 70287360);       // 8388608 B (16 x 512KB)
  _Float16* x0      = (_Float16*)(ws + 78675968);    // 20971520 B [512][64][320]
  float*    bias0   = (float*)(ws + 99647488);       // 8192 B (r,z,nx,nh)
  float*    bias1   = (float*)(ws + 99655680);       // 8192 B
  // total ws use: 99663872 B

  hipMemsetAsync(ws, 0, 1081344, stream);  // flags + pooled = zeros
  prep_x0<<<4096, 256, 0, stream>>>(texts, emb, x0);
  prep_b<<<2, 256, 0, stream>>>(bih0, bhh0, bih1, bhh1, bias0, bias1);
  gru_persistent<<<128, 256, 0, stream>>>(x0, Wih0, Whh0, Wih1, Whh1, bias0, bias1,
                                          h1seq, h2seq, xp0ring, xp1ring, pooled,
                                          flags0, flagsP0, flagsP1, flags1);
  fc_kernel<<<512, 64, 0, stream>>>(pooled, fcW, fcb, out);
}

// Round 10
// 4259.710 us; speedup vs baseline: 1.3484x; 1.0235x over previous
//
#include <hip/hip_runtime.h>

#define T_STEPS 512
#define BB 64
#define EE 300
#define EP 320
#define HH 512
#define HB (BB*HH)        // halves per h slot (65536 B)
#define XPSLOT 524288     // bytes per xp slot: 64 rows * 512 cols * 16B (f32 r,z,n,pad)
#define FS 16             // flag stride in ints (64 B): producer-exclusive cache line

typedef _Float16 f16x8 __attribute__((ext_vector_type(8)));
typedef float f32x4 __attribute__((ext_vector_type(4)));
typedef int i32x4 __attribute__((ext_vector_type(4)));

__device__ __forceinline__ f32x4 mf(f16x8 a, f16x8 b, f32x4 c) {
  return __builtin_amdgcn_mfma_f32_16x16x32_f16(a, b, c, 0, 0, 0);
}

struct HMat { i32x4 q[16]; };   // 64 VGPRs: one lane's 16 A-fragments of a 16-row tile

// 16 back-to-back PLAIN (L2-cached) 16B loads + FULL drain in ONE asm block.
// h slots are WRITE-ONCE per dispatch: first reader on an XCD fills L2 from MALL,
// the other consumer WGs on that XCD hit L2 (~8x less MALL read traffic).
#define LOADS16_PLAIN                                                \
    "global_load_dwordx4 %0,  %16, %17\n\t"                          \
    "global_load_dwordx4 %1,  %16, %17 offset:64\n\t"                \
    "global_load_dwordx4 %2,  %16, %17 offset:128\n\t"               \
    "global_load_dwordx4 %3,  %16, %17 offset:192\n\t"               \
    "global_load_dwordx4 %4,  %16, %17 offset:256\n\t"               \
    "global_load_dwordx4 %5,  %16, %17 offset:320\n\t"               \
    "global_load_dwordx4 %6,  %16, %17 offset:384\n\t"               \
    "global_load_dwordx4 %7,  %16, %17 offset:448\n\t"               \
    "global_load_dwordx4 %8,  %16, %17 offset:512\n\t"               \
    "global_load_dwordx4 %9,  %16, %17 offset:576\n\t"               \
    "global_load_dwordx4 %10, %16, %17 offset:640\n\t"               \
    "global_load_dwordx4 %11, %16, %17 offset:704\n\t"               \
    "global_load_dwordx4 %12, %16, %17 offset:768\n\t"               \
    "global_load_dwordx4 %13, %16, %17 offset:832\n\t"               \
    "global_load_dwordx4 %14, %16, %17 offset:896\n\t"               \
    "global_load_dwordx4 %15, %16, %17 offset:960\n\t"               \
    "s_waitcnt vmcnt(0)"

#define HM_OUTS(m) "=v"((m).q[0]), "=v"((m).q[1]), "=v"((m).q[2]), "=v"((m).q[3]),   \
                   "=v"((m).q[4]), "=v"((m).q[5]), "=v"((m).q[6]), "=v"((m).q[7]),   \
                   "=v"((m).q[8]), "=v"((m).q[9]), "=v"((m).q[10]), "=v"((m).q[11]), \
                   "=v"((m).q[12]), "=v"((m).q[13]), "=v"((m).q[14]), "=v"((m).q[15])

__device__ __forceinline__ void load16_plain(HMat& m, const void* base, int voff) {
  asm volatile(LOADS16_PLAIN : HM_OUTS(m) : "v"(voff), "s"(base) : "memory");
}

// fused: 16 PLAIN h-loads (write-once buffer) + 4 sc1 xp loads (reused ring — MUST
// bypass L2 or a stale line from 16 steps ago could be served), ONE drain.
#define LOADS16_XP4_MIX                                              \
    "global_load_dwordx4 %0,  %20, %21\n\t"                          \
    "global_load_dwordx4 %1,  %20, %21 offset:64\n\t"                \
    "global_load_dwordx4 %2,  %20, %21 offset:128\n\t"               \
    "global_load_dwordx4 %3,  %20, %21 offset:192\n\t"               \
    "global_load_dwordx4 %4,  %20, %21 offset:256\n\t"               \
    "global_load_dwordx4 %5,  %20, %21 offset:320\n\t"               \
    "global_load_dwordx4 %6,  %20, %21 offset:384\n\t"               \
    "global_load_dwordx4 %7,  %20, %21 offset:448\n\t"               \
    "global_load_dwordx4 %8,  %20, %21 offset:512\n\t"               \
    "global_load_dwordx4 %9,  %20, %21 offset:576\n\t"               \
    "global_load_dwordx4 %10, %20, %21 offset:640\n\t"               \
    "global_load_dwordx4 %11, %20, %21 offset:704\n\t"               \
    "global_load_dwordx4 %12, %20, %21 offset:768\n\t"               \
    "global_load_dwordx4 %13, %20, %21 offset:832\n\t"               \
    "global_load_dwordx4 %14, %20, %21 offset:896\n\t"               \
    "global_load_dwordx4 %15, %20, %21 offset:960\n\t"               \
    "global_load_dwordx4 %16, %22, %26 sc1\n\t"                      \
    "global_load_dwordx4 %17, %23, %26 sc1\n\t"                      \
    "global_load_dwordx4 %18, %24, %26 sc1\n\t"                      \
    "global_load_dwordx4 %19, %25, %26 sc1\n\t"                      \
    "s_waitcnt vmcnt(0)"

__device__ __forceinline__ void load_h_xp(HMat& m, f32x4* xp,
                                          const void* hbase, int hvoff,
                                          const void* xbase, const int* vx) {
  asm volatile(LOADS16_XP4_MIX
    : HM_OUTS(m), "=v"(xp[0]), "=v"(xp[1]), "=v"(xp[2]), "=v"(xp[3])
    : "v"(hvoff), "s"(hbase), "v"(vx[0]), "v"(vx[1]), "v"(vx[2]), "v"(vx[3]), "s"(xbase)
    : "memory");
}

__device__ __forceinline__ void load_xp4(f32x4* xp, const void* xbase, const int* vx) {
  asm volatile(
    "global_load_dwordx4 %0, %4, %8 sc1\n\t"
    "global_load_dwordx4 %1, %5, %8 sc1\n\t"
    "global_load_dwordx4 %2, %6, %8 sc1\n\t"
    "global_load_dwordx4 %3, %7, %8 sc1\n\t"
    "s_waitcnt vmcnt(0)"
    : "=v"(xp[0]), "=v"(xp[1]), "=v"(xp[2]), "=v"(xp[3])
    : "v"(vx[0]), "v"(vx[1]), "v"(vx[2]), "v"(vx[3]), "s"(xbase) : "memory");
}

// batched x-prefetch: 10 plain cached loads + full drain (x0 is immutable)
__device__ __forceinline__ void loadx10_wait(i32x4* xq, const void* base, int voff) {
  asm volatile(
    "global_load_dwordx4 %0, %10, %11\n\t"
    "global_load_dwordx4 %1, %10, %11 offset:64\n\t"
    "global_load_dwordx4 %2, %10, %11 offset:128\n\t"
    "global_load_dwordx4 %3, %10, %11 offset:192\n\t"
    "global_load_dwordx4 %4, %10, %11 offset:256\n\t"
    "global_load_dwordx4 %5, %10, %11 offset:320\n\t"
    "global_load_dwordx4 %6, %10, %11 offset:384\n\t"
    "global_load_dwordx4 %7, %10, %11 offset:448\n\t"
    "global_load_dwordx4 %8, %10, %11 offset:512\n\t"
    "global_load_dwordx4 %9, %10, %11 offset:576\n\t"
    "s_waitcnt vmcnt(0)"
    : "=v"(xq[0]), "=v"(xq[1]), "=v"(xq[2]), "=v"(xq[3]), "=v"(xq[4]),
      "=v"(xq[5]), "=v"(xq[6]), "=v"(xq[7]), "=v"(xq[8]), "=v"(xq[9])
    : "v"(voff), "s"(base) : "memory");
}

__device__ __forceinline__ f16x8 fragq(i32x4 q) {
  union { i32x4 i; f16x8 v; } x; x.i = q; return x.v;
}

// publish: write-through to MALL (no L2 allocate) so consumers' L2 fills are fresh
__device__ __forceinline__ void st16_mall(void* p, f16x8 v) {
  i32x4 iv;
  __builtin_memcpy(&iv, &v, 16);
  asm volatile("global_store_dwordx4 %0, %1, off sc0 sc1" :: "v"(p), "v"(iv) : "memory");
}
__device__ __forceinline__ void st16f(void* p, f32x4 v) {
  i32x4 iv;
  __builtin_memcpy(&iv, &v, 16);
  asm volatile("global_store_dwordx4 %0, %1, off sc0 sc1" :: "v"(p), "v"(iv) : "memory");
}
__device__ __forceinline__ void st4_dev(int* p, int v) {
  asm volatile("global_store_dword %0, %1, off sc0 sc1" :: "v"(p), "v"(v) : "memory");
}

// NARROWED per-WAVE poll: lanes 0-31 poll the 32-producer all-to-all set
// (pa[lane*FS] >= ta — the REQUIRED h dependency), lanes 32-63 all poll ONE
// column-matched P-flag (pb >= tb; same address, HW-coalesced to 1 request).
// R8 insight: xp data is column-partitioned, so only producer w matters —
// removing the spurious max-over-32 P-tail from every recurrence detect.
// slp: 1 on critical waits, larger on slack throttles. Targets <=0 trivially pass.
__device__ __forceinline__ void wave_wait(const int* pa, int ta,
                                          const int* pb, int tb, int slp) {
  const int lane = threadIdx.x & 63;
  const int* p = (lane < 32) ? (pa + lane * FS) : pb;
  const int t = (lane < 32) ? ta : tb;
  for (;;) {
    int v;
    asm volatile("global_load_dword %0, %1, off sc1\n\ts_waitcnt vmcnt(0)"
                 : "=v"(v) : "v"(p) : "memory");
    if (__all(v >= t)) return;
    for (int i = 0; i < slp; ++i) __builtin_amdgcn_s_sleep(1);
  }
}

// single-flag wait (all lanes broadcast-load one address: 1 request/iteration)
__device__ __forceinline__ void wait_one(const int* p, int t, int slp) {
  for (;;) {
    int v;
    asm volatile("global_load_dword %0, %1, off sc1\n\ts_waitcnt vmcnt(0)"
                 : "=v"(v) : "v"(p) : "memory");
    if (__all(v >= t)) return;
    for (int i = 0; i < slp; ++i) __builtin_amdgcn_s_sleep(1);
  }
}

__device__ __forceinline__ float sigf(float x) { return 1.f / (1.f + __expf(-x)); }

struct B3 { f16x8 r, z, n; };
// LDS weight read: [chunk][gate(3)][jj(16)][40 halves] — 40-half jj stride spreads the
// 16 cols across bank windows 4*((5*jj+quad) mod 8): uniform, max 2-way (free).
__device__ __forceinline__ B3 ldsB(const _Float16* wl, int chunk, int jj, int kq) {
  B3 o;
  const _Float16* p = wl + chunk * 1920 + jj * 40 + kq;
  o.r = *(const f16x8*)p;
  o.z = *(const f16x8*)(p + 640);
  o.n = *(const f16x8*)(p + 1280);
  return o;
}

__global__ void prep_x0(const int* __restrict__ texts, const float* __restrict__ emb,
                        _Float16* __restrict__ x0) {
  const size_t N = (size_t)T_STEPS * BB * EP;
  const size_t stride = (size_t)gridDim.x * blockDim.x;
  for (size_t i = (size_t)blockIdx.x * blockDim.x + threadIdx.x; i < N; i += stride) {
    int e = (int)(i % EP);
    size_t tb = i / EP;
    float v = 0.f;
    if (e < EE) v = emb[(size_t)texts[tb] * EE + e];
    x0[i] = (_Float16)v;
  }
}

__global__ void prep_b(const float* __restrict__ bih0, const float* __restrict__ bhh0,
                       const float* __restrict__ bih1, const float* __restrict__ bhh1,
                       float* __restrict__ bias0, float* __restrict__ bias1) {
  int i = blockIdx.x * blockDim.x + threadIdx.x;
  if (i < HH) {
    bias0[i]        = bih0[i] + bhh0[i];
    bias0[512 + i]  = bih0[512 + i] + bhh0[512 + i];
    bias0[1024 + i] = bih0[1024 + i];
    bias0[1536 + i] = bhh0[1024 + i];
    bias1[i]        = bih1[i] + bhh1[i];
    bias1[512 + i]  = bih1[512 + i] + bhh1[512 + i];
    bias1[1024 + i] = bih1[1024 + i];
    bias1[1536 + i] = bhh1[1024 + i];
  }
}

// 128 WGs x 256 threads, 4 roles x 32 WGs; each WG = 4 independent waves, one per
// 16-row batch group (GRU rows are independent -> 8 decoupled pipelines).
//   role 0 (L0): h1 recurrence, Whh0 in LDS, consumes precomputed xp0 (f32).
//   role 1 (P0): x0 @ Wih0^T -> xp0 ring (16 slots), runs ~15 steps ahead (off path).
//   role 2 (P1): h1 @ Wih1^T -> xp1 ring (4 slots), pipelined between L0 and L1.
//   role 3 (L1): h2 recurrence, Whh1 in LDS, consumes xp1; pooled atomics in tail.
// h1/h2 are WRITE-ONCE sequences (plain cached consumer loads). xp rings stay sc1,
// and are COLUMN-PARTITIONED: consumer w depends only on P-producer w (waits
// narrowed to a single flag line for every xp/throttle condition).
__global__ __launch_bounds__(256, 1) void gru_persistent(
    const _Float16* __restrict__ x0,
    const float* __restrict__ Wih0, const float* __restrict__ Whh0,
    const float* __restrict__ Wih1, const float* __restrict__ Whh1,
    const float* __restrict__ bias0, const float* __restrict__ bias1,
    _Float16* h1seq, _Float16* h2seq, float* xp0ring, float* xp1ring,
    float* pooled, int* flags0, int* flagsP0, int* flagsP1, int* flags1)
{
  const int wg   = blockIdx.x;
  const int role = wg >> 5;          // 0=L0 1=P0 2=P1 3=L1
  const int w    = wg & 31;          // column slice 0..31
  const int jb   = w * 16;           // 16 h-cols per WG
  const int tid  = threadIdx.x;
  const int g    = tid >> 6;         // wave = batch group, rows g*16..+15
  const int lane = tid & 63;
  const int quad = lane >> 4;
  const int l15  = lane & 15;
  const int kq   = quad * 8;
  const int hoff = (g * 16 + l15) * 1024 + quad * 16;  // byte voffset into an h slot

  __shared__ alignas(16) _Float16 wlds[30720];     // 16 chunks x 1920 halves = 60 KiB
  __shared__ alignas(16) _Float16 tile[4][16][16]; // per-wave publish transpose, 2 KiB

  // ---- one-time LDS weight fill (fp32 global -> f16, 40-half jj stride) ----
  {
    const float* Wsrc = (role == 0) ? Whh0 : (role == 1) ? Wih0
                      : (role == 2) ? Wih1 : Whh1;
    const int nch  = (role == 1) ? 10 : 16;
    const int Ksrc = (role == 1) ? EE : HH;
    for (int idx = tid; idx < nch * 192; idx += 256) {
      int q = idx & 3, jj = (idx >> 2) & 15, g3 = (idx >> 6) % 3, ch = idx / 192;
      int row = g3 * 512 + jb + jj;
      _Float16* dst = wlds + ch * 1920 + g3 * 640 + jj * 40 + q * 8;
      int colb = ch * 32 + q * 8;
      #pragma unroll
      for (int e = 0; e < 8; ++e) {
        int col = colb + e;
        dst[e] = (col < Ksrc) ? (_Float16)Wsrc[(size_t)row * Ksrc + col] : (_Float16)0.f;
      }
    }
  }
  __syncthreads();

  // loop-invariant xp voffsets: [row 64][hcol 512][gate pad4] f32 -> row stride 8192 B
  int vx[4];
  #pragma unroll
  for (int rg = 0; rg < 4; ++rg)
    vx[rg] = (g * 16 + quad * 4 + rg) * 8192 + (jb + l15) * 16;

  const int* fg0  = flags0  + g * 32 * FS;   // 32 producers x 64B per group
  const int* fgP0 = flagsP0 + g * 32 * FS;
  const int* fgP1 = flagsP1 + g * 32 * FS;
  const int* fg1  = flags1  + g * 32 * FS;

  if (role == 0) {            // ---------------- L0: h1 recurrence ----------------
    const int j = jb + l15;
    const float br = bias0[j], bz = bias0[512 + j];
    const float bnx = bias0[1024 + j], bnh = bias0[1536 + j];
    int* myf = flags0 + (g * 32 + w) * FS;
    const int* pP0w = fgP0 + w * FS;           // single column-matched P0 flag
    float hprev[4] = {0.f, 0.f, 0.f, 0.f};
    _Float16 (*tc)[16] = tile[g];
    for (int s = 0; s < T_STEPS; ++s) {
      // h dep: all 32 L0 producers >= s. xp dep: ONLY P0 WG w >= s+1.
      wave_wait(fg0, s, pP0w, s + 1, 1);
      f32x4 hR = {0.f,0.f,0.f,0.f}, hZ = {0.f,0.f,0.f,0.f}, hN = {0.f,0.f,0.f,0.f};
      f32x4 xp[4];
      const void* xb = (const char*)xp0ring + (size_t)(s & 15) * XPSLOT;
      if (s >= 1) {
        HMat hA;
        load_h_xp(hA, xp, h1seq + (size_t)(s - 1) * HB, hoff, xb, vx);
        #pragma unroll 4
        for (int c = 0; c < 16; ++c) {
          f16x8 a = fragq(hA.q[c]);
          B3 bb = ldsB(wlds, c, l15, kq);
          hR = mf(a, bb.r, hR); hZ = mf(a, bb.z, hZ); hN = mf(a, bb.n, hN);
        }
      } else {
        load_xp4(xp, xb, vx);
      }
      #pragma unroll
      for (int rg = 0; rg < 4; ++rg) {
        float r = sigf(xp[rg][0] + hR[rg] + br);
        float z = sigf(xp[rg][1] + hZ[rg] + bz);
        float n = tanhf(xp[rg][2] + bnx + r * (hN[rg] + bnh));
        float hnew = (1.f - z) * n + z * hprev[rg];
        hprev[rg] = hnew;
        tc[quad * 4 + rg][l15] = (_Float16)hnew;
      }
      if (lane < 32) {                      // 16 rows x 32B per wave
        int row = lane & 15, hb = lane >> 4;
        f16x8 v = *(const f16x8*)&tc[row][hb * 8];
        st16_mall(h1seq + (size_t)s * HB
                  + (size_t)(g * 16 + row) * HH + jb + hb * 8, v);
      }
      __builtin_amdgcn_s_waitcnt(0);
      if (lane == 0) st4_dev(myf, s + 1);
    }
  } else if (role == 1) {     // ---------------- P0: x projection (ahead) ----------------
    int* myf = flagsP0 + (g * 32 + w) * FS;
    const int* pL0w = fg0 + w * FS;            // only L0 WG w consumes our slice
    const int xoff = (g * 16 + l15) * 640 + quad * 16;
    for (int t = 0; t < T_STEPS; ++t) {
      // ring throttle vs our single consumer — SLACK: slow sampling
      wait_one(pL0w, t - 15, 8);
      i32x4 xq[10];
      loadx10_wait(xq, x0 + (size_t)t * BB * EP, xoff);
      f32x4 aR = {0.f,0.f,0.f,0.f}, aZ = {0.f,0.f,0.f,0.f}, aN = {0.f,0.f,0.f,0.f};
      #pragma unroll 5
      for (int c = 0; c < 10; ++c) {
        f16x8 a = fragq(xq[c]);
        B3 bb = ldsB(wlds, c, l15, kq);
        aR = mf(a, bb.r, aR); aZ = mf(a, bb.z, aZ); aN = mf(a, bb.n, aN);
      }
      char* xb = (char*)xp0ring + (size_t)(t & 15) * XPSLOT;
      #pragma unroll
      for (int rg = 0; rg < 4; ++rg) {
        f32x4 v = {aR[rg], aZ[rg], aN[rg], 0.f};
        st16f(xb + vx[rg], v);
      }
      __builtin_amdgcn_s_waitcnt(0);
      if (lane == 0) st4_dev(myf, t + 1);
    }
  } else if (role == 2) {     // ---------------- P1: h1 -> xp1 projection ----------------
    int* myf = flagsP1 + (g * 32 + w) * FS;
    const int* pL1w = fg1 + w * FS;            // only L1 WG w consumes our slice
    for (int t = 0; t < T_STEPS; ++t) {
      // h1[t] dep: all 32 L0 producers (full row). Ring throttle: single L1 flag.
      wave_wait(fg0, t + 1, pL1w, t - 3, 1);
      HMat A;
      load16_plain(A, h1seq + (size_t)t * HB, hoff);
      f32x4 aR = {0.f,0.f,0.f,0.f}, aZ = {0.f,0.f,0.f,0.f}, aN = {0.f,0.f,0.f,0.f};
      #pragma unroll 4
      for (int c = 0; c < 16; ++c) {
        f16x8 a = fragq(A.q[c]);
        B3 bb = ldsB(wlds, c, l15, kq);
        aR = mf(a, bb.r, aR); aZ = mf(a, bb.z, aZ); aN = mf(a, bb.n, aN);
      }
      char* xb = (char*)xp1ring + (size_t)(t & 3) * XPSLOT;
      #pragma unroll
      for (int rg = 0; rg < 4; ++rg) {
        f32x4 v = {aR[rg], aZ[rg], aN[rg], 0.f};
        st16f(xb + vx[rg], v);
      }
      __builtin_amdgcn_s_waitcnt(0);
      if (lane == 0) st4_dev(myf, t + 1);
    }
  } else {                    // ---------------- L1: h2 recurrence ----------------
    const int j = jb + l15;
    const float br = bias1[j], bz = bias1[512 + j];
    const float bnx = bias1[1024 + j], bnh = bias1[1536 + j];
    int* myf = flags1 + (g * 32 + w) * FS;
    const int* pP1w = fgP1 + w * FS;           // single column-matched P1 flag
    float hprev[4] = {0.f, 0.f, 0.f, 0.f};
    _Float16 (*tc)[16] = tile[g];
    for (int t = 0; t < T_STEPS; ++t) {
      // h dep: all 32 L1 producers >= t. xp dep: ONLY P1 WG w >= t+1.
      wave_wait(fg1, t, pP1w, t + 1, 1);
      f32x4 hR = {0.f,0.f,0.f,0.f}, hZ = {0.f,0.f,0.f,0.f}, hN = {0.f,0.f,0.f,0.f};
      f32x4 xp[4];
      const void* xb = (const char*)xp1ring + (size_t)(t & 3) * XPSLOT;
      if (t >= 1) {
        HMat hA;
        load_h_xp(hA, xp, h2seq + (size_t)(t - 1) * HB, hoff, xb, vx);
        #pragma unroll 4
        for (int c = 0; c < 16; ++c) {
          f16x8 a = fragq(hA.q[c]);
          B3 bb = ldsB(wlds, c, l15, kq);
          hR = mf(a, bb.r, hR); hZ = mf(a, bb.z, hZ); hN = mf(a, bb.n, hN);
        }
      } else {
        load_xp4(xp, xb, vx);
      }
      #pragma unroll
      for (int rg = 0; rg < 4; ++rg) {
        float r = sigf(xp[rg][0] + hR[rg] + br);
        float z = sigf(xp[rg][1] + hZ[rg] + bz);
        float n = tanhf(xp[rg][2] + bnx + r * (hN[rg] + bnh));
        float hnew = (1.f - z) * n + z * hprev[rg];
        hprev[rg] = hnew;
        tc[quad * 4 + rg][l15] = (_Float16)hnew;
      }
      if (lane < 32) {
        int row = lane & 15, hb = lane >> 4;
        f16x8 v = *(const f16x8*)&tc[row][hb * 8];
        st16_mall(h2seq + (size_t)t * HB
                  + (size_t)(g * 16 + row) * HH + jb + hb * 8, v);
      }
      __builtin_amdgcn_s_waitcnt(0);
      if (lane == 0) st4_dev(myf, t + 1);
      // tail (off the flag path): pooled partial sums, raw; /64 in FC
      if (lane < 16) {
        float sum = 0.f;
        #pragma unroll
        for (int r = 0; r < 16; ++r) sum += (float)tc[r][lane];
        atomicAdd(pooled + (size_t)t * HH + jb + lane, sum);
      }
    }
  }
}

__global__ void fc_kernel(const float* __restrict__ pooled, const float* __restrict__ fcW,
                          const float* __restrict__ fcb, float* __restrict__ out) {
  const int t = blockIdx.x;
  const int lane = threadIdx.x;  // 64 = one wave
  float a0 = 0.f, a1 = 0.f, a2 = 0.f, a3 = 0.f, a4 = 0.f;
  for (int jj = lane; jj < HH; jj += 64) {
    float p = pooled[(size_t)t * HH + jj];
    a0 += p * fcW[jj];
    a1 += p * fcW[512 + jj];
    a2 += p * fcW[1024 + jj];
    a3 += p * fcW[1536 + jj];
    a4 += p * fcW[2048 + jj];
  }
  #pragma unroll
  for (int off = 32; off > 0; off >>= 1) {
    a0 += __shfl_down(a0, off, 64);
    a1 += __shfl_down(a1, off, 64);
    a2 += __shfl_down(a2, off, 64);
    a3 += __shfl_down(a3, off, 64);
    a4 += __shfl_down(a4, off, 64);
  }
  if (lane == 0) {
    const float sc = 1.f / 64.f;
    out[t * 5 + 0] = a0 * sc + fcb[0];
    out[t * 5 + 1] = a1 * sc + fcb[1];
    out[t * 5 + 2] = a2 * sc + fcb[2];
    out[t * 5 + 3] = a3 * sc + fcb[3];
    out[t * 5 + 4] = a4 * sc + fcb[4];
  }
}

extern "C" void kernel_launch(void* const* d_in, const int* in_sizes, int n_in,
                              void* d_out, int out_size, void* d_ws, size_t ws_size,
                              hipStream_t stream) {
  const int*   texts = (const int*)  d_in[0];
  const float* emb   = (const float*)d_in[1];
  const float* Wih0  = (const float*)d_in[2];
  const float* Whh0  = (const float*)d_in[3];
  const float* bih0  = (const float*)d_in[4];
  const float* bhh0  = (const float*)d_in[5];
  const float* Wih1  = (const float*)d_in[6];
  const float* Whh1  = (const float*)d_in[7];
  const float* bih1  = (const float*)d_in[8];
  const float* bhh1  = (const float*)d_in[9];
  const float* fcW   = (const float*)d_in[10];
  const float* fcb   = (const float*)d_in[11];
  float* out = (float*)d_out;

  char* ws = (char*)d_ws;
  int*      flags0  = (int*)ws;                      // 8192 B (4 grp x 32 x 64B)
  int*      flagsP0 = (int*)(ws + 8192);             // 8192 B
  int*      flagsP1 = (int*)(ws + 16384);            // 8192 B
  int*      flags1  = (int*)(ws + 24576);            // 8192 B
  float*    pooled  = (float*)(ws + 32768);          // 1048576 B [512][512] f32
  _Float16* h1seq   = (_Float16*)(ws + 1081344);     // 33554432 B (512 x 64KB, write-once)
  _Float16* h2seq   = (_Float16*)(ws + 34635776);    // 33554432 B (512 x 64KB, write-once)
  float*    xp1ring = (float*)(ws + 68190208);       // 2097152 B (4 x 512KB)
  float*    xp0ring = (float*)(ws + 70287360);       // 8388608 B (16 x 512KB)
  _Float16* x0      = (_Float16*)(ws + 78675968);    // 20971520 B [512][64][320]
  float*    bias0   = (float*)(ws + 99647488);       // 8192 B (r,z,nx,nh)
  float*    bias1   = (float*)(ws + 99655680);       // 8192 B
  // total ws use: 99663872 B

  hipMemsetAsync(ws, 0, 1081344, stream);  // flags + pooled = zeros
  prep_x0<<<4096, 256, 0, stream>>>(texts, emb, x0);
  prep_b<<<2, 256, 0, stream>>>(bih0, bhh0, bih1, bhh1, bias0, bias1);
  gru_persistent<<<128, 256, 0, stream>>>(x0, Wih0, Whh0, Wih1, Whh1, bias0, bias1,
                                          h1seq, h2seq, xp0ring, xp1ring, pooled,
                                          flags0, flagsP0, flagsP1, flags1);
  fc_kernel<<<512, 64, 0, stream>>>(pooled, fcW, fcb, out);
}

// Round 11
// 2818.973 us; speedup vs baseline: 2.0376x; 1.5111x over previous
//
#include <hip/hip_runtime.h>

#define T_STEPS 512
#define BB 64
#define EE 300
#define EP 320
#define HH 512
#define HB (BB*HH)        // halves per h slot (65536 B)
#define XPSLOT 524288     // bytes per xp slot: 64 rows * 512 cols * 16B (f32 r,z,n,pad)
#define FS 16             // flag stride in ints (64 B): producer-exclusive cache line

typedef _Float16 f16x8 __attribute__((ext_vector_type(8)));
typedef float f32x4 __attribute__((ext_vector_type(4)));
typedef int i32x4 __attribute__((ext_vector_type(4)));

__device__ __forceinline__ f32x4 mf(f16x8 a, f16x8 b, f32x4 c) {
  return __builtin_amdgcn_mfma_f32_16x16x32_f16(a, b, c, 0, 0, 0);
}

// ---- split-K load blocks (write-once h buffers -> PLAIN cached loads) ----
// half A: 8 plain h loads (cols 0-255) + 4 sc1 xp loads + 1 sc1 flag-B PROBE,
// one drain. The probe rides the data drain: zero extra round-trips. Flags are
// monotone, so a stale "ready" probe is still valid when checked later.
#define LOADS8H_XP4P                                                 \
    "global_load_dwordx4 %0,  %13, %14\n\t"                          \
    "global_load_dwordx4 %1,  %13, %14 offset:64\n\t"                \
    "global_load_dwordx4 %2,  %13, %14 offset:128\n\t"               \
    "global_load_dwordx4 %3,  %13, %14 offset:192\n\t"               \
    "global_load_dwordx4 %4,  %13, %14 offset:256\n\t"               \
    "global_load_dwordx4 %5,  %13, %14 offset:320\n\t"               \
    "global_load_dwordx4 %6,  %13, %14 offset:384\n\t"               \
    "global_load_dwordx4 %7,  %13, %14 offset:448\n\t"               \
    "global_load_dwordx4 %8,  %15, %19 sc1\n\t"                      \
    "global_load_dwordx4 %9,  %16, %19 sc1\n\t"                      \
    "global_load_dwordx4 %10, %17, %19 sc1\n\t"                      \
    "global_load_dwordx4 %11, %18, %19 sc1\n\t"                      \
    "global_load_dword   %12, %20, off sc1\n\t"                      \
    "s_waitcnt vmcnt(0)"

__device__ __forceinline__ void load_h8a_xp_probe(i32x4* q, f32x4* xp, int* pb,
    const void* hbase, int hvoff, const void* xbase, const int* vx,
    const int* probe) {
  asm volatile(LOADS8H_XP4P
    : "=v"(q[0]), "=v"(q[1]), "=v"(q[2]), "=v"(q[3]),
      "=v"(q[4]), "=v"(q[5]), "=v"(q[6]), "=v"(q[7]),
      "=v"(xp[0]), "=v"(xp[1]), "=v"(xp[2]), "=v"(xp[3]), "=v"(*pb)
    : "v"(hvoff), "s"(hbase), "v"(vx[0]), "v"(vx[1]), "v"(vx[2]), "v"(vx[3]),
      "s"(xbase), "v"(probe)
    : "memory");
}

// half A for P1: 8 plain h loads + flag-B probe, one drain
__device__ __forceinline__ void load_h8a_probe(i32x4* q, int* pb,
    const void* hbase, int hvoff, const int* probe) {
  asm volatile(
    "global_load_dwordx4 %0, %9, %10\n\t"
    "global_load_dwordx4 %1, %9, %10 offset:64\n\t"
    "global_load_dwordx4 %2, %9, %10 offset:128\n\t"
    "global_load_dwordx4 %3, %9, %10 offset:192\n\t"
    "global_load_dwordx4 %4, %9, %10 offset:256\n\t"
    "global_load_dwordx4 %5, %9, %10 offset:320\n\t"
    "global_load_dwordx4 %6, %9, %10 offset:384\n\t"
    "global_load_dwordx4 %7, %9, %10 offset:448\n\t"
    "global_load_dword   %8, %11, off sc1\n\t"
    "s_waitcnt vmcnt(0)"
    : "=v"(q[0]), "=v"(q[1]), "=v"(q[2]), "=v"(q[3]),
      "=v"(q[4]), "=v"(q[5]), "=v"(q[6]), "=v"(q[7]), "=v"(*pb)
    : "v"(hvoff), "s"(hbase), "v"(probe) : "memory");
}

// half B: 8 plain h loads (cols 256-511) + drain
__device__ __forceinline__ void load_h8b(i32x4* q, const void* hbase, int hvoff) {
  asm volatile(
    "global_load_dwordx4 %0, %8, %9 offset:512\n\t"
    "global_load_dwordx4 %1, %8, %9 offset:576\n\t"
    "global_load_dwordx4 %2, %8, %9 offset:640\n\t"
    "global_load_dwordx4 %3, %8, %9 offset:704\n\t"
    "global_load_dwordx4 %4, %8, %9 offset:768\n\t"
    "global_load_dwordx4 %5, %8, %9 offset:832\n\t"
    "global_load_dwordx4 %6, %8, %9 offset:896\n\t"
    "global_load_dwordx4 %7, %8, %9 offset:960\n\t"
    "s_waitcnt vmcnt(0)"
    : "=v"(q[0]), "=v"(q[1]), "=v"(q[2]), "=v"(q[3]),
      "=v"(q[4]), "=v"(q[5]), "=v"(q[6]), "=v"(q[7])
    : "v"(hvoff), "s"(hbase) : "memory");
}

__device__ __forceinline__ void load_xp4(f32x4* xp, const void* xbase, const int* vx) {
  asm volatile(
    "global_load_dwordx4 %0, %4, %8 sc1\n\t"
    "global_load_dwordx4 %1, %5, %8 sc1\n\t"
    "global_load_dwordx4 %2, %6, %8 sc1\n\t"
    "global_load_dwordx4 %3, %7, %8 sc1\n\t"
    "s_waitcnt vmcnt(0)"
    : "=v"(xp[0]), "=v"(xp[1]), "=v"(xp[2]), "=v"(xp[3])
    : "v"(vx[0]), "v"(vx[1]), "v"(vx[2]), "v"(vx[3]), "s"(xbase) : "memory");
}

// batched x-prefetch: 10 plain cached loads + full drain (x0 is immutable)
__device__ __forceinline__ void loadx10_wait(i32x4* xq, const void* base, int voff) {
  asm volatile(
    "global_load_dwordx4 %0, %10, %11\n\t"
    "global_load_dwordx4 %1, %10, %11 offset:64\n\t"
    "global_load_dwordx4 %2, %10, %11 offset:128\n\t"
    "global_load_dwordx4 %3, %10, %11 offset:192\n\t"
    "global_load_dwordx4 %4, %10, %11 offset:256\n\t"
    "global_load_dwordx4 %5, %10, %11 offset:320\n\t"
    "global_load_dwordx4 %6, %10, %11 offset:384\n\t"
    "global_load_dwordx4 %7, %10, %11 offset:448\n\t"
    "global_load_dwordx4 %8, %10, %11 offset:512\n\t"
    "global_load_dwordx4 %9, %10, %11 offset:576\n\t"
    "s_waitcnt vmcnt(0)"
    : "=v"(xq[0]), "=v"(xq[1]), "=v"(xq[2]), "=v"(xq[3]), "=v"(xq[4]),
      "=v"(xq[5]), "=v"(xq[6]), "=v"(xq[7]), "=v"(xq[8]), "=v"(xq[9])
    : "v"(voff), "s"(base) : "memory");
}

__device__ __forceinline__ f16x8 fragq(i32x4 q) {
  union { i32x4 i; f16x8 v; } x; x.i = q; return x.v;
}

// publish: write-through to MALL (no L2 allocate) so consumers' L2 fills are fresh
__device__ __forceinline__ void st16_mall(void* p, f16x8 v) {
  i32x4 iv;
  __builtin_memcpy(&iv, &v, 16);
  asm volatile("global_store_dwordx4 %0, %1, off sc0 sc1" :: "v"(p), "v"(iv) : "memory");
}
__device__ __forceinline__ void st16f(void* p, f32x4 v) {
  i32x4 iv;
  __builtin_memcpy(&iv, &v, 16);
  asm volatile("global_store_dwordx4 %0, %1, off sc0 sc1" :: "v"(p), "v"(iv) : "memory");
}
__device__ __forceinline__ void st4_dev(int* p, int v) {
  asm volatile("global_store_dword %0, %1, off sc0 sc1" :: "v"(p), "v"(v) : "memory");
}

// half-A wait: lanes 0-31 poll the 16 half-A producer lines (2 dup lanes each),
// lanes 32-63 poll ONE column-matched xp flag (broadcast-coalesced).
__device__ __forceinline__ void wait16_plus1(const int* b16, int t16,
                                             const int* pone, int tone, int slp) {
  const int lane = threadIdx.x & 63;
  const int* p = (lane < 32) ? (b16 + (lane & 15) * FS) : pone;
  const int t = (lane < 32) ? t16 : tone;
  for (;;) {
    int v;
    asm volatile("global_load_dword %0, %1, off sc1\n\ts_waitcnt vmcnt(0)"
                 : "=v"(v) : "v"(p) : "memory");
    if (__all(v >= t)) return;
    for (int i = 0; i < slp; ++i) __builtin_amdgcn_s_sleep(1);
  }
}

// 16-producer wait (half-B fallback when the optimistic probe missed)
__device__ __forceinline__ void wait16(const int* base, int t, int slp) {
  const int* p = base + (threadIdx.x & 15) * FS;
  for (;;) {
    int v;
    asm volatile("global_load_dword %0, %1, off sc1\n\ts_waitcnt vmcnt(0)"
                 : "=v"(v) : "v"(p) : "memory");
    if (__all(v >= t)) return;
    for (int i = 0; i < slp; ++i) __builtin_amdgcn_s_sleep(1);
  }
}

// single-flag wait (all lanes broadcast-load one address)
__device__ __forceinline__ void wait_one(const int* p, int t, int slp) {
  for (;;) {
    int v;
    asm volatile("global_load_dword %0, %1, off sc1\n\ts_waitcnt vmcnt(0)"
                 : "=v"(v) : "v"(p) : "memory");
    if (__all(v >= t)) return;
    for (int i = 0; i < slp; ++i) __builtin_amdgcn_s_sleep(1);
  }
}

__device__ __forceinline__ float sigf(float x) { return 1.f / (1.f + __expf(-x)); }

struct B3 { f16x8 r, z, n; };
// LDS weight read: [chunk][gate(3)][jj(16)][40 halves] — 40-half jj stride spreads the
// 16 cols across bank windows 4*((5*jj+quad) mod 8): uniform, max 2-way (free).
__device__ __forceinline__ B3 ldsB(const _Float16* wl, int chunk, int jj, int kq) {
  B3 o;
  const _Float16* p = wl + chunk * 1920 + jj * 40 + kq;
  o.r = *(const f16x8*)p;
  o.z = *(const f16x8*)(p + 640);
  o.n = *(const f16x8*)(p + 1280);
  return o;
}

__global__ void prep_x0(const int* __restrict__ texts, const float* __restrict__ emb,
                        _Float16* __restrict__ x0) {
  const size_t N = (size_t)T_STEPS * BB * EP;
  const size_t stride = (size_t)gridDim.x * blockDim.x;
  for (size_t i = (size_t)blockIdx.x * blockDim.x + threadIdx.x; i < N; i += stride) {
    int e = (int)(i % EP);
    size_t tb = i / EP;
    float v = 0.f;
    if (e < EE) v = emb[(size_t)texts[tb] * EE + e];
    x0[i] = (_Float16)v;
  }
}

__global__ void prep_b(const float* __restrict__ bih0, const float* __restrict__ bhh0,
                       const float* __restrict__ bih1, const float* __restrict__ bhh1,
                       float* __restrict__ bias0, float* __restrict__ bias1) {
  int i = blockIdx.x * blockDim.x + threadIdx.x;
  if (i < HH) {
    bias0[i]        = bih0[i] + bhh0[i];
    bias0[512 + i]  = bih0[512 + i] + bhh0[512 + i];
    bias0[1024 + i] = bih0[1024 + i];
    bias0[1536 + i] = bhh0[1024 + i];
    bias1[i]        = bih1[i] + bhh1[i];
    bias1[512 + i]  = bih1[512 + i] + bhh1[512 + i];
    bias1[1024 + i] = bih1[1024 + i];
    bias1[1536 + i] = bhh1[1024 + i];
  }
}

// 128 WGs x 256 threads, 4 roles x 32 WGs; each WG = 4 independent waves, one per
// 16-row batch group. SPLIT-K recurrence detect: wait half-A producers (max16),
// load half-A + probe half-B flag in one drain, MFMA half-A, then half-B with the
// (usually satisfied) probe — hides the B-tail behind half-A load+compute.
// h1/h2 WRITE-ONCE sequences (plain cached loads); xp rings sc1, column-matched
// single-flag deps (R10). pooled -> per-group partial stores, no atomics.
__global__ __launch_bounds__(256, 1) void gru_persistent(
    const _Float16* __restrict__ x0,
    const float* __restrict__ Wih0, const float* __restrict__ Whh0,
    const float* __restrict__ Wih1, const float* __restrict__ Whh1,
    const float* __restrict__ bias0, const float* __restrict__ bias1,
    _Float16* h1seq, _Float16* h2seq, float* xp0ring, float* xp1ring,
    float* pooledPart, int* flags0, int* flagsP0, int* flagsP1, int* flags1)
{
  const int wg   = blockIdx.x;
  const int role = wg >> 5;          // 0=L0 1=P0 2=P1 3=L1
  const int w    = wg & 31;          // column slice 0..31
  const int jb   = w * 16;           // 16 h-cols per WG
  const int tid  = threadIdx.x;
  const int g    = tid >> 6;         // wave = batch group, rows g*16..+15
  const int lane = tid & 63;
  const int quad = lane >> 4;
  const int l15  = lane & 15;
  const int kq   = quad * 8;
  const int hoff = (g * 16 + l15) * 1024 + quad * 16;  // byte voffset into an h slot

  __shared__ alignas(16) _Float16 wlds[30720];     // 16 chunks x 1920 halves = 60 KiB
  __shared__ alignas(16) _Float16 tile[4][16][16]; // per-wave publish transpose, 2 KiB

  // ---- one-time LDS weight fill (fp32 global -> f16, 40-half jj stride) ----
  {
    const float* Wsrc = (role == 0) ? Whh0 : (role == 1) ? Wih0
                      : (role == 2) ? Wih1 : Whh1;
    const int nch  = (role == 1) ? 10 : 16;
    const int Ksrc = (role == 1) ? EE : HH;
    for (int idx = tid; idx < nch * 192; idx += 256) {
      int q = idx & 3, jj = (idx >> 2) & 15, g3 = (idx >> 6) % 3, ch = idx / 192;
      int row = g3 * 512 + jb + jj;
      _Float16* dst = wlds + ch * 1920 + g3 * 640 + jj * 40 + q * 8;
      int colb = ch * 32 + q * 8;
      #pragma unroll
      for (int e = 0; e < 8; ++e) {
        int col = colb + e;
        dst[e] = (col < Ksrc) ? (_Float16)Wsrc[(size_t)row * Ksrc + col] : (_Float16)0.f;
      }
    }
  }
  __syncthreads();

  // loop-invariant xp voffsets: [row 64][hcol 512][gate pad4] f32 -> row stride 8192 B
  int vx[4];
  #pragma unroll
  for (int rg = 0; rg < 4; ++rg)
    vx[rg] = (g * 16 + quad * 4 + rg) * 8192 + (jb + l15) * 16;

  const int* fg0  = flags0  + g * 32 * FS;   // 32 producers x 64B per group
  const int* fgP0 = flagsP0 + g * 32 * FS;
  const int* fgP1 = flagsP1 + g * 32 * FS;
  const int* fg1  = flags1  + g * 32 * FS;

  if (role == 0) {            // ---------------- L0: h1 recurrence ----------------
    const int j = jb + l15;
    const float br = bias0[j], bz = bias0[512 + j];
    const float bnx = bias0[1024 + j], bnh = bias0[1536 + j];
    int* myf = flags0 + (g * 32 + w) * FS;
    const int* pP0w  = fgP0 + w * FS;               // single column-matched P0 flag
    const int* prbB  = fg0 + (16 + l15) * FS;       // per-lane half-B probe address
    float hprev[4] = {0.f, 0.f, 0.f, 0.f};
    _Float16 (*tc)[16] = tile[g];
    for (int s = 0; s < T_STEPS; ++s) {
      // half-A h dep (producers 0-15) + xp dep (P0 WG w only)
      wait16_plus1(fg0, s, pP0w, s + 1, 1);
      f32x4 hR = {0.f,0.f,0.f,0.f}, hZ = {0.f,0.f,0.f,0.f}, hN = {0.f,0.f,0.f,0.f};
      f32x4 xp[4];
      const void* xb = (const char*)xp0ring + (size_t)(s & 15) * XPSLOT;
      if (s >= 1) {
        const void* hb = h1seq + (size_t)(s - 1) * HB;
        i32x4 qa[8]; int pb;
        load_h8a_xp_probe(qa, xp, &pb, hb, hoff, xb, vx, prbB);
        #pragma unroll 4
        for (int c = 0; c < 8; ++c) {
          f16x8 a = fragq(qa[c]);
          B3 bb = ldsB(wlds, c, l15, kq);
          hR = mf(a, bb.r, hR); hZ = mf(a, bb.z, hZ); hN = mf(a, bb.n, hN);
        }
        if (!__all(pb >= s)) wait16(fg0 + 16 * FS, s, 1);  // B-tail (rare)
        i32x4 qbv[8];
        load_h8b(qbv, hb, hoff);
        #pragma unroll 4
        for (int c = 0; c < 8; ++c) {
          f16x8 a = fragq(qbv[c]);
          B3 bb = ldsB(wlds, 8 + c, l15, kq);
          hR = mf(a, bb.r, hR); hZ = mf(a, bb.z, hZ); hN = mf(a, bb.n, hN);
        }
      } else {
        load_xp4(xp, xb, vx);
      }
      #pragma unroll
      for (int rg = 0; rg < 4; ++rg) {
        float r = sigf(xp[rg][0] + hR[rg] + br);
        float z = sigf(xp[rg][1] + hZ[rg] + bz);
        float n = tanhf(xp[rg][2] + bnx + r * (hN[rg] + bnh));
        float hnew = (1.f - z) * n + z * hprev[rg];
        hprev[rg] = hnew;
        tc[quad * 4 + rg][l15] = (_Float16)hnew;
      }
      if (lane < 32) {                      // 16 rows x 32B per wave
        int row = lane & 15, hb2 = lane >> 4;
        f16x8 v = *(const f16x8*)&tc[row][hb2 * 8];
        st16_mall(h1seq + (size_t)s * HB
                  + (size_t)(g * 16 + row) * HH + jb + hb2 * 8, v);
      }
      __builtin_amdgcn_s_waitcnt(0);
      if (lane == 0) st4_dev(myf, s + 1);
    }
  } else if (role == 1) {     // ---------------- P0: x projection (ahead) ----------------
    int* myf = flagsP0 + (g * 32 + w) * FS;
    const int* pL0w = fg0 + w * FS;            // only L0 WG w consumes our slice
    const int xoff = (g * 16 + l15) * 640 + quad * 16;
    for (int t = 0; t < T_STEPS; ++t) {
      wait_one(pL0w, t - 15, 8);               // ring throttle — slack, slow sampling
      i32x4 xq[10];
      loadx10_wait(xq, x0 + (size_t)t * BB * EP, xoff);
      f32x4 aR = {0.f,0.f,0.f,0.f}, aZ = {0.f,0.f,0.f,0.f}, aN = {0.f,0.f,0.f,0.f};
      #pragma unroll 5
      for (int c = 0; c < 10; ++c) {
        f16x8 a = fragq(xq[c]);
        B3 bb = ldsB(wlds, c, l15, kq);
        aR = mf(a, bb.r, aR); aZ = mf(a, bb.z, aZ); aN = mf(a, bb.n, aN);
      }
      char* xb = (char*)xp0ring + (size_t)(t & 15) * XPSLOT;
      #pragma unroll
      for (int rg = 0; rg < 4; ++rg) {
        f32x4 v = {aR[rg], aZ[rg], aN[rg], 0.f};
        st16f(xb + vx[rg], v);
      }
      __builtin_amdgcn_s_waitcnt(0);
      if (lane == 0) st4_dev(myf, t + 1);
    }
  } else if (role == 2) {     // ---------------- P1: h1 -> xp1 projection ----------------
    int* myf = flagsP1 + (g * 32 + w) * FS;
    const int* pL1w = fg1 + w * FS;            // only L1 WG w consumes our slice
    const int* prbB = fg0 + (16 + l15) * FS;
    for (int t = 0; t < T_STEPS; ++t) {
      // half-A of h1[t] (producers 0-15 >= t+1); ring throttle single L1 flag
      wait16_plus1(fg0, t + 1, pL1w, t - 3, 1);
      const void* hb = h1seq + (size_t)t * HB;
      i32x4 qa[8]; int pb;
      load_h8a_probe(qa, &pb, hb, hoff, prbB);
      f32x4 aR = {0.f,0.f,0.f,0.f}, aZ = {0.f,0.f,0.f,0.f}, aN = {0.f,0.f,0.f,0.f};
      #pragma unroll 4
      for (int c = 0; c < 8; ++c) {
        f16x8 a = fragq(qa[c]);
        B3 bb = ldsB(wlds, c, l15, kq);
        aR = mf(a, bb.r, aR); aZ = mf(a, bb.z, aZ); aN = mf(a, bb.n, aN);
      }
      if (!__all(pb >= t + 1)) wait16(fg0 + 16 * FS, t + 1, 1);
      i32x4 qbv[8];
      load_h8b(qbv, hb, hoff);
      #pragma unroll 4
      for (int c = 0; c < 8; ++c) {
        f16x8 a = fragq(qbv[c]);
        B3 bb = ldsB(wlds, 8 + c, l15, kq);
        aR = mf(a, bb.r, aR); aZ = mf(a, bb.z, aZ); aN = mf(a, bb.n, aN);
      }
      char* xb = (char*)xp1ring + (size_t)(t & 3) * XPSLOT;
      #pragma unroll
      for (int rg = 0; rg < 4; ++rg) {
        f32x4 v = {aR[rg], aZ[rg], aN[rg], 0.f};
        st16f(xb + vx[rg], v);
      }
      __builtin_amdgcn_s_waitcnt(0);
      if (lane == 0) st4_dev(myf, t + 1);
    }
  } else {                    // ---------------- L1: h2 recurrence ----------------
    const int j = jb + l15;
    const float br = bias1[j], bz = bias1[512 + j];
    const float bnx = bias1[1024 + j], bnh = bias1[1536 + j];
    int* myf = flags1 + (g * 32 + w) * FS;
    const int* pP1w = fgP1 + w * FS;           // single column-matched P1 flag
    const int* prbB = fg1 + (16 + l15) * FS;
    float* ppB = pooledPart + ((size_t)g * T_STEPS) * HH + jb;
    float hprev[4] = {0.f, 0.f, 0.f, 0.f};
    _Float16 (*tc)[16] = tile[g];
    for (int t = 0; t < T_STEPS; ++t) {
      // half-A h dep (producers 0-15 >= t) + xp dep (P1 WG w only >= t+1)
      wait16_plus1(fg1, t, pP1w, t + 1, 1);
      f32x4 hR = {0.f,0.f,0.f,0.f}, hZ = {0.f,0.f,0.f,0.f}, hN = {0.f,0.f,0.f,0.f};
      f32x4 xp[4];
      const void* xb = (const char*)xp1ring + (size_t)(t & 3) * XPSLOT;
      if (t >= 1) {
        const void* hb = h2seq + (size_t)(t - 1) * HB;
        i32x4 qa[8]; int pb;
        load_h8a_xp_probe(qa, xp, &pb, hb, hoff, xb, vx, prbB);
        #pragma unroll 4
        for (int c = 0; c < 8; ++c) {
          f16x8 a = fragq(qa[c]);
          B3 bb = ldsB(wlds, c, l15, kq);
          hR = mf(a, bb.r, hR); hZ = mf(a, bb.z, hZ); hN = mf(a, bb.n, hN);
        }
        if (!__all(pb >= t)) wait16(fg1 + 16 * FS, t, 1);
        i32x4 qbv[8];
        load_h8b(qbv, hb, hoff);
        #pragma unroll 4
        for (int c = 0; c < 8; ++c) {
          f16x8 a = fragq(qbv[c]);
          B3 bb = ldsB(wlds, 8 + c, l15, kq);
          hR = mf(a, bb.r, hR); hZ = mf(a, bb.z, hZ); hN = mf(a, bb.n, hN);
        }
      } else {
        load_xp4(xp, xb, vx);
      }
      #pragma unroll
      for (int rg = 0; rg < 4; ++rg) {
        float r = sigf(xp[rg][0] + hR[rg] + br);
        float z = sigf(xp[rg][1] + hZ[rg] + bz);
        float n = tanhf(xp[rg][2] + bnx + r * (hN[rg] + bnh));
        float hnew = (1.f - z) * n + z * hprev[rg];
        hprev[rg] = hnew;
        tc[quad * 4 + rg][l15] = (_Float16)hnew;
      }
      if (lane < 32) {
        int row = lane & 15, hb2 = lane >> 4;
        f16x8 v = *(const f16x8*)&tc[row][hb2 * 8];
        st16_mall(h2seq + (size_t)t * HB
                  + (size_t)(g * 16 + row) * HH + jb + hb2 * 8, v);
      }
      __builtin_amdgcn_s_waitcnt(0);
      if (lane == 0) st4_dev(myf, t + 1);
      // tail (off the flag path): per-group pooled partial, PLAIN store (write-once,
      // visible to fc_kernel at dispatch boundary; no atomic RMW fabric traffic)
      if (lane < 16) {
        float sum = 0.f;
        #pragma unroll
        for (int r = 0; r < 16; ++r) sum += (float)tc[r][lane];
        ppB[(size_t)t * HH + lane] = sum;
      }
    }
  }
}

__global__ void fc_kernel(const float* __restrict__ pooledPart,
                          const float* __restrict__ fcW,
                          const float* __restrict__ fcb, float* __restrict__ out) {
  const int t = blockIdx.x;
  const int lane = threadIdx.x;  // 64 = one wave
  const size_t GS = (size_t)T_STEPS * HH;   // per-group partial stride
  float a0 = 0.f, a1 = 0.f, a2 = 0.f, a3 = 0.f, a4 = 0.f;
  for (int jj = lane; jj < HH; jj += 64) {
    size_t idx = (size_t)t * HH + jj;
    float p = pooledPart[idx] + pooledPart[GS + idx]
            + pooledPart[2 * GS + idx] + pooledPart[3 * GS + idx];
    a0 += p * fcW[jj];
    a1 += p * fcW[512 + jj];
    a2 += p * fcW[1024 + jj];
    a3 += p * fcW[1536 + jj];
    a4 += p * fcW[2048 + jj];
  }
  #pragma unroll
  for (int off = 32; off > 0; off >>= 1) {
    a0 += __shfl_down(a0, off, 64);
    a1 += __shfl_down(a1, off, 64);
    a2 += __shfl_down(a2, off, 64);
    a3 += __shfl_down(a3, off, 64);
    a4 += __shfl_down(a4, off, 64);
  }
  if (lane == 0) {
    const float sc = 1.f / 64.f;
    out[t * 5 + 0] = a0 * sc + fcb[0];
    out[t * 5 + 1] = a1 * sc + fcb[1];
    out[t * 5 + 2] = a2 * sc + fcb[2];
    out[t * 5 + 3] = a3 * sc + fcb[3];
    out[t * 5 + 4] = a4 * sc + fcb[4];
  }
}

extern "C" void kernel_launch(void* const* d_in, const int* in_sizes, int n_in,
                              void* d_out, int out_size, void* d_ws, size_t ws_size,
                              hipStream_t stream) {
  const int*   texts = (const int*)  d_in[0];
  const float* emb   = (const float*)d_in[1];
  const float* Wih0  = (const float*)d_in[2];
  const float* Whh0  = (const float*)d_in[3];
  const float* bih0  = (const float*)d_in[4];
  const float* bhh0  = (const float*)d_in[5];
  const float* Wih1  = (const float*)d_in[6];
  const float* Whh1  = (const float*)d_in[7];
  const float* bih1  = (const float*)d_in[8];
  const float* bhh1  = (const float*)d_in[9];
  const float* fcW   = (const float*)d_in[10];
  const float* fcb   = (const float*)d_in[11];
  float* out = (float*)d_out;

  char* ws = (char*)d_ws;
  int*      flags0   = (int*)ws;                     // 8192 B (4 grp x 32 x 64B)
  int*      flagsP0  = (int*)(ws + 8192);            // 8192 B
  int*      flagsP1  = (int*)(ws + 16384);           // 8192 B
  int*      flags1   = (int*)(ws + 24576);           // 8192 B
  float*    pooledPt = (float*)(ws + 32768);         // 4194304 B [4][512][512] f32
  _Float16* h1seq    = (_Float16*)(ws + 4227072);    // 33554432 B (512 x 64KB, write-once)
  _Float16* h2seq    = (_Float16*)(ws + 37781504);   // 33554432 B (512 x 64KB, write-once)
  float*    xp1ring  = (float*)(ws + 71335936);      // 2097152 B (4 x 512KB)
  float*    xp0ring  = (float*)(ws + 73433088);      // 8388608 B (16 x 512KB)
  _Float16* x0       = (_Float16*)(ws + 81821696);   // 20971520 B [512][64][320]
  float*    bias0    = (float*)(ws + 102793216);     // 8192 B (r,z,nx,nh)
  float*    bias1    = (float*)(ws + 102801408);     // 8192 B
  // total ws use: 102809600 B

  hipMemsetAsync(ws, 0, 32768, stream);  // flags only (pooledPart fully overwritten)
  prep_x0<<<4096, 256, 0, stream>>>(texts, emb, x0);
  prep_b<<<2, 256, 0, stream>>>(bih0, bhh0, bih1, bhh1, bias0, bias1);
  gru_persistent<<<128, 256, 0, stream>>>(x0, Wih0, Whh0, Wih1, Whh1, bias0, bias1,
                                          h1seq, h2seq, xp0ring, xp1ring, pooledPt,
                                          flags0, flagsP0, flagsP1, flags1);
  fc_kernel<<<512, 64, 0, stream>>>(pooledPt, fcW, fcb, out);
}

// Round 12
// 2746.909 us; speedup vs baseline: 2.0910x; 1.0262x over previous
//
#include <hip/hip_runtime.h>

#define T_STEPS 512
#define BB 64
#define EE 300
#define EP 320
#define HH 512
#define HB (BB*HH)        // halves per h slot (65536 B)
#define XPSLOT 524288     // bytes per xp slot: 64 rows * 512 cols * 16B (f32 r,z,n,pad)
#define FS 16             // flag stride in ints (64 B): producer-exclusive cache line

typedef _Float16 f16x8 __attribute__((ext_vector_type(8)));
typedef float f32x4 __attribute__((ext_vector_type(4)));
typedef int i32x4 __attribute__((ext_vector_type(4)));

__device__ __forceinline__ f32x4 mf(f16x8 a, f16x8 b, f32x4 c) {
  return __builtin_amdgcn_mfma_f32_16x16x32_f16(a, b, c, 0, 0, 0);
}

// ---- 3-phase progressive split-K load blocks (write-once h -> PLAIN loads) ----
// Phase A: chunks 0-3 (cols 0-127, producers 0-7) + 4 sc1 xp loads + sc1 probe of
// producers 8-15, ONE drain. Probes ride data drains: zero extra round-trips.
// Flags are monotone, so a stale "ready" probe is still valid when checked later.
__device__ __forceinline__ void load_h4a_xp_probe(i32x4* q, f32x4* xp, int* pb,
    const void* hbase, int hvoff, const void* xbase, const int* vx,
    const int* probe) {
  asm volatile(
    "global_load_dwordx4 %0, %9,  %10\n\t"
    "global_load_dwordx4 %1, %9,  %10 offset:64\n\t"
    "global_load_dwordx4 %2, %9,  %10 offset:128\n\t"
    "global_load_dwordx4 %3, %9,  %10 offset:192\n\t"
    "global_load_dwordx4 %4, %11, %15 sc1\n\t"
    "global_load_dwordx4 %5, %12, %15 sc1\n\t"
    "global_load_dwordx4 %6, %13, %15 sc1\n\t"
    "global_load_dwordx4 %7, %14, %15 sc1\n\t"
    "global_load_dword   %8, %16, off sc1\n\t"
    "s_waitcnt vmcnt(0)"
    : "=v"(q[0]), "=v"(q[1]), "=v"(q[2]), "=v"(q[3]),
      "=v"(xp[0]), "=v"(xp[1]), "=v"(xp[2]), "=v"(xp[3]), "=v"(*pb)
    : "v"(hvoff), "s"(hbase), "v"(vx[0]), "v"(vx[1]), "v"(vx[2]), "v"(vx[3]),
      "s"(xbase), "v"(probe)
    : "memory");
}

// Phase A for P1: chunks 0-3 + probe(8-15), one drain
__device__ __forceinline__ void load_h4a_probe(i32x4* q, int* pb,
    const void* hbase, int hvoff, const int* probe) {
  asm volatile(
    "global_load_dwordx4 %0, %5, %6\n\t"
    "global_load_dwordx4 %1, %5, %6 offset:64\n\t"
    "global_load_dwordx4 %2, %5, %6 offset:128\n\t"
    "global_load_dwordx4 %3, %5, %6 offset:192\n\t"
    "global_load_dword   %4, %7, off sc1\n\t"
    "s_waitcnt vmcnt(0)"
    : "=v"(q[0]), "=v"(q[1]), "=v"(q[2]), "=v"(q[3]), "=v"(*pb)
    : "v"(hvoff), "s"(hbase), "v"(probe) : "memory");
}

// Phase B: chunks 4-7 (cols 128-255, producers 8-15) + probe(16-31), one drain
__device__ __forceinline__ void load_h4b_probe(i32x4* q, int* pc,
    const void* hbase, int hvoff, const int* probe) {
  asm volatile(
    "global_load_dwordx4 %0, %5, %6 offset:256\n\t"
    "global_load_dwordx4 %1, %5, %6 offset:320\n\t"
    "global_load_dwordx4 %2, %5, %6 offset:384\n\t"
    "global_load_dwordx4 %3, %5, %6 offset:448\n\t"
    "global_load_dword   %4, %7, off sc1\n\t"
    "s_waitcnt vmcnt(0)"
    : "=v"(q[0]), "=v"(q[1]), "=v"(q[2]), "=v"(q[3]), "=v"(*pc)
    : "v"(hvoff), "s"(hbase), "v"(probe) : "memory");
}

// Phase C: chunks 8-15 (cols 256-511, producers 16-31), one drain
__device__ __forceinline__ void load_h8c(i32x4* q, const void* hbase, int hvoff) {
  asm volatile(
    "global_load_dwordx4 %0, %8, %9 offset:512\n\t"
    "global_load_dwordx4 %1, %8, %9 offset:576\n\t"
    "global_load_dwordx4 %2, %8, %9 offset:640\n\t"
    "global_load_dwordx4 %3, %8, %9 offset:704\n\t"
    "global_load_dwordx4 %4, %8, %9 offset:768\n\t"
    "global_load_dwordx4 %5, %8, %9 offset:832\n\t"
    "global_load_dwordx4 %6, %8, %9 offset:896\n\t"
    "global_load_dwordx4 %7, %8, %9 offset:960\n\t"
    "s_waitcnt vmcnt(0)"
    : "=v"(q[0]), "=v"(q[1]), "=v"(q[2]), "=v"(q[3]),
      "=v"(q[4]), "=v"(q[5]), "=v"(q[6]), "=v"(q[7])
    : "v"(hvoff), "s"(hbase) : "memory");
}

__device__ __forceinline__ void load_xp4(f32x4* xp, const void* xbase, const int* vx) {
  asm volatile(
    "global_load_dwordx4 %0, %4, %8 sc1\n\t"
    "global_load_dwordx4 %1, %5, %8 sc1\n\t"
    "global_load_dwordx4 %2, %6, %8 sc1\n\t"
    "global_load_dwordx4 %3, %7, %8 sc1\n\t"
    "s_waitcnt vmcnt(0)"
    : "=v"(xp[0]), "=v"(xp[1]), "=v"(xp[2]), "=v"(xp[3])
    : "v"(vx[0]), "v"(vx[1]), "v"(vx[2]), "v"(vx[3]), "s"(xbase) : "memory");
}

// batched x-prefetch: 10 plain cached loads + full drain (x0 is immutable)
__device__ __forceinline__ void loadx10_wait(i32x4* xq, const void* base, int voff) {
  asm volatile(
    "global_load_dwordx4 %0, %10, %11\n\t"
    "global_load_dwordx4 %1, %10, %11 offset:64\n\t"
    "global_load_dwordx4 %2, %10, %11 offset:128\n\t"
    "global_load_dwordx4 %3, %10, %11 offset:192\n\t"
    "global_load_dwordx4 %4, %10, %11 offset:256\n\t"
    "global_load_dwordx4 %5, %10, %11 offset:320\n\t"
    "global_load_dwordx4 %6, %10, %11 offset:384\n\t"
    "global_load_dwordx4 %7, %10, %11 offset:448\n\t"
    "global_load_dwordx4 %8, %10, %11 offset:512\n\t"
    "global_load_dwordx4 %9, %10, %11 offset:576\n\t"
    "s_waitcnt vmcnt(0)"
    : "=v"(xq[0]), "=v"(xq[1]), "=v"(xq[2]), "=v"(xq[3]), "=v"(xq[4]),
      "=v"(xq[5]), "=v"(xq[6]), "=v"(xq[7]), "=v"(xq[8]), "=v"(xq[9])
    : "v"(voff), "s"(base) : "memory");
}

__device__ __forceinline__ f16x8 fragq(i32x4 q) {
  union { i32x4 i; f16x8 v; } x; x.i = q; return x.v;
}

// publish: write-through to MALL (no L2 allocate) so consumers' L2 fills are fresh
__device__ __forceinline__ void st16_mall(void* p, f16x8 v) {
  i32x4 iv;
  __builtin_memcpy(&iv, &v, 16);
  asm volatile("global_store_dwordx4 %0, %1, off sc0 sc1" :: "v"(p), "v"(iv) : "memory");
}
__device__ __forceinline__ void st16f(void* p, f32x4 v) {
  i32x4 iv;
  __builtin_memcpy(&iv, &v, 16);
  asm volatile("global_store_dwordx4 %0, %1, off sc0 sc1" :: "v"(p), "v"(iv) : "memory");
}
__device__ __forceinline__ void st4_dev(int* p, int v) {
  asm volatile("global_store_dword %0, %1, off sc0 sc1" :: "v"(p), "v"(v) : "memory");
}

// leading wait: lanes 0-31 poll the 8 phase-A producer lines (4 dup lanes each),
// lanes 32-63 poll ONE column-matched xp flag (broadcast-coalesced).
__device__ __forceinline__ void wait8_plus1(const int* b8, int t8,
                                            const int* pone, int tone, int slp) {
  const int lane = threadIdx.x & 63;
  const int* p = (lane < 32) ? (b8 + (lane & 7) * FS) : pone;
  const int t = (lane < 32) ? t8 : tone;
  for (;;) {
    int v;
    asm volatile("global_load_dword %0, %1, off sc1\n\ts_waitcnt vmcnt(0)"
                 : "=v"(v) : "v"(p) : "memory");
    if (__all(v >= t)) return;
    for (int i = 0; i < slp; ++i) __builtin_amdgcn_s_sleep(1);
  }
}

// fallback waits when an optimistic probe missed (rare)
__device__ __forceinline__ void wait8(const int* base, int t, int slp) {
  const int* p = base + (threadIdx.x & 7) * FS;
  for (;;) {
    int v;
    asm volatile("global_load_dword %0, %1, off sc1\n\ts_waitcnt vmcnt(0)"
                 : "=v"(v) : "v"(p) : "memory");
    if (__all(v >= t)) return;
    for (int i = 0; i < slp; ++i) __builtin_amdgcn_s_sleep(1);
  }
}
__device__ __forceinline__ void wait16(const int* base, int t, int slp) {
  const int* p = base + (threadIdx.x & 15) * FS;
  for (;;) {
    int v;
    asm volatile("global_load_dword %0, %1, off sc1\n\ts_waitcnt vmcnt(0)"
                 : "=v"(v) : "v"(p) : "memory");
    if (__all(v >= t)) return;
    for (int i = 0; i < slp; ++i) __builtin_amdgcn_s_sleep(1);
  }
}

// single-flag wait (all lanes broadcast-load one address)
__device__ __forceinline__ void wait_one(const int* p, int t, int slp) {
  for (;;) {
    int v;
    asm volatile("global_load_dword %0, %1, off sc1\n\ts_waitcnt vmcnt(0)"
                 : "=v"(v) : "v"(p) : "memory");
    if (__all(v >= t)) return;
    for (int i = 0; i < slp; ++i) __builtin_amdgcn_s_sleep(1);
  }
}

__device__ __forceinline__ float sigf(float x) { return 1.f / (1.f + __expf(-x)); }

struct B3 { f16x8 r, z, n; };
// LDS weight read: [chunk][gate(3)][jj(16)][40 halves] — 40-half jj stride spreads the
// 16 cols across bank windows 4*((5*jj+quad) mod 8): uniform, max 2-way (free).
__device__ __forceinline__ B3 ldsB(const _Float16* wl, int chunk, int jj, int kq) {
  B3 o;
  const _Float16* p = wl + chunk * 1920 + jj * 40 + kq;
  o.r = *(const f16x8*)p;
  o.z = *(const f16x8*)(p + 640);
  o.n = *(const f16x8*)(p + 1280);
  return o;
}

__global__ void prep_x0(const int* __restrict__ texts, const float* __restrict__ emb,
                        _Float16* __restrict__ x0) {
  const size_t N = (size_t)T_STEPS * BB * EP;
  const size_t stride = (size_t)gridDim.x * blockDim.x;
  for (size_t i = (size_t)blockIdx.x * blockDim.x + threadIdx.x; i < N; i += stride) {
    int e = (int)(i % EP);
    size_t tb = i / EP;
    float v = 0.f;
    if (e < EE) v = emb[(size_t)texts[tb] * EE + e];
    x0[i] = (_Float16)v;
  }
}

__global__ void prep_b(const float* __restrict__ bih0, const float* __restrict__ bhh0,
                       const float* __restrict__ bih1, const float* __restrict__ bhh1,
                       float* __restrict__ bias0, float* __restrict__ bias1) {
  int i = blockIdx.x * blockDim.x + threadIdx.x;
  if (i < HH) {
    bias0[i]        = bih0[i] + bhh0[i];
    bias0[512 + i]  = bih0[512 + i] + bhh0[512 + i];
    bias0[1024 + i] = bih0[1024 + i];
    bias0[1536 + i] = bhh0[1024 + i];
    bias1[i]        = bih1[i] + bhh1[i];
    bias1[512 + i]  = bih1[512 + i] + bhh1[512 + i];
    bias1[1024 + i] = bih1[1024 + i];
    bias1[1536 + i] = bhh1[1024 + i];
  }
}

// 128 WGs x 256 threads, 4 roles x 32 WGs; each WG = 4 independent waves, one per
// 16-row batch group. 3-PHASE PROGRESSIVE split-K detect: wait only producers 0-7
// (max8) + xp flag; each later producer-set's readiness is probed via a flag load
// riding the previous data drain and checked from registers — tails hide behind
// accumulated load+MFMA cover. h1/h2 WRITE-ONCE (plain cached loads); xp rings
// sc1 with column-matched single-flag deps; pooled partials are plain stores.
__global__ __launch_bounds__(256, 1) void gru_persistent(
    const _Float16* __restrict__ x0,
    const float* __restrict__ Wih0, const float* __restrict__ Whh0,
    const float* __restrict__ Wih1, const float* __restrict__ Whh1,
    const float* __restrict__ bias0, const float* __restrict__ bias1,
    _Float16* h1seq, _Float16* h2seq, float* xp0ring, float* xp1ring,
    float* pooledPart, int* flags0, int* flagsP0, int* flagsP1, int* flags1)
{
  const int wg   = blockIdx.x;
  const int role = wg >> 5;          // 0=L0 1=P0 2=P1 3=L1
  const int w    = wg & 31;          // column slice 0..31
  const int jb   = w * 16;           // 16 h-cols per WG
  const int tid  = threadIdx.x;
  const int g    = tid >> 6;         // wave = batch group, rows g*16..+15
  const int lane = tid & 63;
  const int quad = lane >> 4;
  const int l15  = lane & 15;
  const int kq   = quad * 8;
  const int hoff = (g * 16 + l15) * 1024 + quad * 16;  // byte voffset into an h slot

  __shared__ alignas(16) _Float16 wlds[30720];     // 16 chunks x 1920 halves = 60 KiB
  __shared__ alignas(16) _Float16 tile[4][16][16]; // per-wave publish transpose, 2 KiB

  // ---- one-time LDS weight fill (fp32 global -> f16, 40-half jj stride) ----
  {
    const float* Wsrc = (role == 0) ? Whh0 : (role == 1) ? Wih0
                      : (role == 2) ? Wih1 : Whh1;
    const int nch  = (role == 1) ? 10 : 16;
    const int Ksrc = (role == 1) ? EE : HH;
    for (int idx = tid; idx < nch * 192; idx += 256) {
      int q = idx & 3, jj = (idx >> 2) & 15, g3 = (idx >> 6) % 3, ch = idx / 192;
      int row = g3 * 512 + jb + jj;
      _Float16* dst = wlds + ch * 1920 + g3 * 640 + jj * 40 + q * 8;
      int colb = ch * 32 + q * 8;
      #pragma unroll
      for (int e = 0; e < 8; ++e) {
        int col = colb + e;
        dst[e] = (col < Ksrc) ? (_Float16)Wsrc[(size_t)row * Ksrc + col] : (_Float16)0.f;
      }
    }
  }
  __syncthreads();

  // loop-invariant xp voffsets: [row 64][hcol 512][gate pad4] f32 -> row stride 8192 B
  int vx[4];
  #pragma unroll
  for (int rg = 0; rg < 4; ++rg)
    vx[rg] = (g * 16 + quad * 4 + rg) * 8192 + (jb + l15) * 16;

  const int* fg0  = flags0  + g * 32 * FS;   // 32 producers x 64B per group
  const int* fgP0 = flagsP0 + g * 32 * FS;
  const int* fgP1 = flagsP1 + g * 32 * FS;
  const int* fg1  = flags1  + g * 32 * FS;

  if (role == 0) {            // ---------------- L0: h1 recurrence ----------------
    const int j = jb + l15;
    const float br = bias0[j], bz = bias0[512 + j];
    const float bnx = bias0[1024 + j], bnh = bias0[1536 + j];
    int* myf = flags0 + (g * 32 + w) * FS;
    const int* pP0w = fgP0 + w * FS;                 // single column-matched P0 flag
    const int* prbB = fg0 + (8 + (l15 & 7)) * FS;    // producers 8-15 probe addr
    const int* prbC = fg0 + (16 + l15) * FS;         // producers 16-31 probe addr
    float hprev[4] = {0.f, 0.f, 0.f, 0.f};
    _Float16 (*tc)[16] = tile[g];
    for (int s = 0; s < T_STEPS; ++s) {
      // phase-A h dep (producers 0-7) + xp dep (P0 WG w only)
      wait8_plus1(fg0, s, pP0w, s + 1, 1);
      f32x4 hR = {0.f,0.f,0.f,0.f}, hZ = {0.f,0.f,0.f,0.f}, hN = {0.f,0.f,0.f,0.f};
      f32x4 xp[4];
      const void* xb = (const char*)xp0ring + (size_t)(s & 15) * XPSLOT;
      if (s >= 1) {
        const void* hb = h1seq + (size_t)(s - 1) * HB;
        i32x4 qa[4]; int pb;
        load_h4a_xp_probe(qa, xp, &pb, hb, hoff, xb, vx, prbB);
        #pragma unroll
        for (int c = 0; c < 4; ++c) {
          f16x8 a = fragq(qa[c]);
          B3 bb = ldsB(wlds, c, l15, kq);
          hR = mf(a, bb.r, hR); hZ = mf(a, bb.z, hZ); hN = mf(a, bb.n, hN);
        }
        if (!__all(pb >= s)) wait8(fg0 + 8 * FS, s, 1);
        i32x4 qb[4]; int pc;
        load_h4b_probe(qb, &pc, hb, hoff, prbC);
        #pragma unroll
        for (int c = 0; c < 4; ++c) {
          f16x8 a = fragq(qb[c]);
          B3 bb = ldsB(wlds, 4 + c, l15, kq);
          hR = mf(a, bb.r, hR); hZ = mf(a, bb.z, hZ); hN = mf(a, bb.n, hN);
        }
        if (!__all(pc >= s)) wait16(fg0 + 16 * FS, s, 1);
        i32x4 qc[8];
        load_h8c(qc, hb, hoff);
        #pragma unroll 4
        for (int c = 0; c < 8; ++c) {
          f16x8 a = fragq(qc[c]);
          B3 bb = ldsB(wlds, 8 + c, l15, kq);
          hR = mf(a, bb.r, hR); hZ = mf(a, bb.z, hZ); hN = mf(a, bb.n, hN);
        }
      } else {
        load_xp4(xp, xb, vx);
      }
      #pragma unroll
      for (int rg = 0; rg < 4; ++rg) {
        float r = sigf(xp[rg][0] + hR[rg] + br);
        float z = sigf(xp[rg][1] + hZ[rg] + bz);
        float n = tanhf(xp[rg][2] + bnx + r * (hN[rg] + bnh));
        float hnew = (1.f - z) * n + z * hprev[rg];
        hprev[rg] = hnew;
        tc[quad * 4 + rg][l15] = (_Float16)hnew;
      }
      if (lane < 32) {                      // 16 rows x 32B per wave
        int row = lane & 15, hb2 = lane >> 4;
        f16x8 v = *(const f16x8*)&tc[row][hb2 * 8];
        st16_mall(h1seq + (size_t)s * HB
                  + (size_t)(g * 16 + row) * HH + jb + hb2 * 8, v);
      }
      __builtin_amdgcn_s_waitcnt(0);
      if (lane == 0) st4_dev(myf, s + 1);
    }
  } else if (role == 1) {     // ---------------- P0: x projection (ahead) ----------------
    int* myf = flagsP0 + (g * 32 + w) * FS;
    const int* pL0w = fg0 + w * FS;            // only L0 WG w consumes our slice
    const int xoff = (g * 16 + l15) * 640 + quad * 16;
    for (int t = 0; t < T_STEPS; ++t) {
      wait_one(pL0w, t - 15, 8);               // ring throttle — slack, slow sampling
      i32x4 xq[10];
      loadx10_wait(xq, x0 + (size_t)t * BB * EP, xoff);
      f32x4 aR = {0.f,0.f,0.f,0.f}, aZ = {0.f,0.f,0.f,0.f}, aN = {0.f,0.f,0.f,0.f};
      #pragma unroll 5
      for (int c = 0; c < 10; ++c) {
        f16x8 a = fragq(xq[c]);
        B3 bb = ldsB(wlds, c, l15, kq);
        aR = mf(a, bb.r, aR); aZ = mf(a, bb.z, aZ); aN = mf(a, bb.n, aN);
      }
      char* xb = (char*)xp0ring + (size_t)(t & 15) * XPSLOT;
      #pragma unroll
      for (int rg = 0; rg < 4; ++rg) {
        f32x4 v = {aR[rg], aZ[rg], aN[rg], 0.f};
        st16f(xb + vx[rg], v);
      }
      __builtin_amdgcn_s_waitcnt(0);
      if (lane == 0) st4_dev(myf, t + 1);
    }
  } else if (role == 2) {     // ---------------- P1: h1 -> xp1 projection ----------------
    int* myf = flagsP1 + (g * 32 + w) * FS;
    const int* pL1w = fg1 + w * FS;            // only L1 WG w consumes our slice
    const int* prbB = fg0 + (8 + (l15 & 7)) * FS;
    const int* prbC = fg0 + (16 + l15) * FS;
    for (int t = 0; t < T_STEPS; ++t) {
      // phase-A of h1[t] (producers 0-7 >= t+1); ring throttle single L1 flag
      wait8_plus1(fg0, t + 1, pL1w, t - 3, 1);
      const void* hb = h1seq + (size_t)t * HB;
      i32x4 qa[4]; int pb;
      load_h4a_probe(qa, &pb, hb, hoff, prbB);
      f32x4 aR = {0.f,0.f,0.f,0.f}, aZ = {0.f,0.f,0.f,0.f}, aN = {0.f,0.f,0.f,0.f};
      #pragma unroll
      for (int c = 0; c < 4; ++c) {
        f16x8 a = fragq(qa[c]);
        B3 bb = ldsB(wlds, c, l15, kq);
        aR = mf(a, bb.r, aR); aZ = mf(a, bb.z, aZ); aN = mf(a, bb.n, aN);
      }
      if (!__all(pb >= t + 1)) wait8(fg0 + 8 * FS, t + 1, 1);
      i32x4 qb[4]; int pc;
      load_h4b_probe(qb, &pc, hb, hoff, prbC);
      #pragma unroll
      for (int c = 0; c < 4; ++c) {
        f16x8 a = fragq(qb[c]);
        B3 bb = ldsB(wlds, 4 + c, l15, kq);
        aR = mf(a, bb.r, aR); aZ = mf(a, bb.z, aZ); aN = mf(a, bb.n, aN);
      }
      if (!__all(pc >= t + 1)) wait16(fg0 + 16 * FS, t + 1, 1);
      i32x4 qc[8];
      load_h8c(qc, hb, hoff);
      #pragma unroll 4
      for (int c = 0; c < 8; ++c) {
        f16x8 a = fragq(qc[c]);
        B3 bb = ldsB(wlds, 8 + c, l15, kq);
        aR = mf(a, bb.r, aR); aZ = mf(a, bb.z, aZ); aN = mf(a, bb.n, aN);
      }
      char* xb = (char*)xp1ring + (size_t)(t & 3) * XPSLOT;
      #pragma unroll
      for (int rg = 0; rg < 4; ++rg) {
        f32x4 v = {aR[rg], aZ[rg], aN[rg], 0.f};
        st16f(xb + vx[rg], v);
      }
      __builtin_amdgcn_s_waitcnt(0);
      if (lane == 0) st4_dev(myf, t + 1);
    }
  } else {                    // ---------------- L1: h2 recurrence ----------------
    const int j = jb + l15;
    const float br = bias1[j], bz = bias1[512 + j];
    const float bnx = bias1[1024 + j], bnh = bias1[1536 + j];
    int* myf = flags1 + (g * 32 + w) * FS;
    const int* pP1w = fgP1 + w * FS;           // single column-matched P1 flag
    const int* prbB = fg1 + (8 + (l15 & 7)) * FS;
    const int* prbC = fg1 + (16 + l15) * FS;
    float* ppB = pooledPart + ((size_t)g * T_STEPS) * HH + jb;
    float hprev[4] = {0.f, 0.f, 0.f, 0.f};
    _Float16 (*tc)[16] = tile[g];
    for (int t = 0; t < T_STEPS; ++t) {
      // phase-A h dep (producers 0-7 >= t) + xp dep (P1 WG w only >= t+1)
      wait8_plus1(fg1, t, pP1w, t + 1, 1);
      f32x4 hR = {0.f,0.f,0.f,0.f}, hZ = {0.f,0.f,0.f,0.f}, hN = {0.f,0.f,0.f,0.f};
      f32x4 xp[4];
      const void* xb = (const char*)xp1ring + (size_t)(t & 3) * XPSLOT;
      if (t >= 1) {
        const void* hb = h2seq + (size_t)(t - 1) * HB;
        i32x4 qa[4]; int pb;
        load_h4a_xp_probe(qa, xp, &pb, hb, hoff, xb, vx, prbB);
        #pragma unroll
        for (int c = 0; c < 4; ++c) {
          f16x8 a = fragq(qa[c]);
          B3 bb = ldsB(wlds, c, l15, kq);
          hR = mf(a, bb.r, hR); hZ = mf(a, bb.z, hZ); hN = mf(a, bb.n, hN);
        }
        if (!__all(pb >= t)) wait8(fg1 + 8 * FS, t, 1);
        i32x4 qb[4]; int pc;
        load_h4b_probe(qb, &pc, hb, hoff, prbC);
        #pragma unroll
        for (int c = 0; c < 4; ++c) {
          f16x8 a = fragq(qb[c]);
          B3 bb = ldsB(wlds, 4 + c, l15, kq);
          hR = mf(a, bb.r, hR); hZ = mf(a, bb.z, hZ); hN = mf(a, bb.n, hN);
        }
        if (!__all(pc >= t)) wait16(fg1 + 16 * FS, t, 1);
        i32x4 qc[8];
        load_h8c(qc, hb, hoff);
        #pragma unroll 4
        for (int c = 0; c < 8; ++c) {
          f16x8 a = fragq(qc[c]);
          B3 bb = ldsB(wlds, 8 + c, l15, kq);
          hR = mf(a, bb.r, hR); hZ = mf(a, bb.z, hZ); hN = mf(a, bb.n, hN);
        }
      } else {
        load_xp4(xp, xb, vx);
      }
      #pragma unroll
      for (int rg = 0; rg < 4; ++rg) {
        float r = sigf(xp[rg][0] + hR[rg] + br);
        float z = sigf(xp[rg][1] + hZ[rg] + bz);
        float n = tanhf(xp[rg][2] + bnx + r * (hN[rg] + bnh));
        float hnew = (1.f - z) * n + z * hprev[rg];
        hprev[rg] = hnew;
        tc[quad * 4 + rg][l15] = (_Float16)hnew;
      }
      if (lane < 32) {
        int row = lane & 15, hb2 = lane >> 4;
        f16x8 v = *(const f16x8*)&tc[row][hb2 * 8];
        st16_mall(h2seq + (size_t)t * HB
                  + (size_t)(g * 16 + row) * HH + jb + hb2 * 8, v);
      }
      __builtin_amdgcn_s_waitcnt(0);
      if (lane == 0) st4_dev(myf, t + 1);
      // tail (off the flag path): per-group pooled partial, PLAIN store (write-once)
      if (lane < 16) {
        float sum = 0.f;
        #pragma unroll
        for (int r = 0; r < 16; ++r) sum += (float)tc[r][lane];
        ppB[(size_t)t * HH + lane] = sum;
      }
    }
  }
}

__global__ void fc_kernel(const float* __restrict__ pooledPart,
                          const float* __restrict__ fcW,
                          const float* __restrict__ fcb, float* __restrict__ out) {
  const int t = blockIdx.x;
  const int lane = threadIdx.x;  // 64 = one wave
  const size_t GS = (size_t)T_STEPS * HH;   // per-group partial stride
  float a0 = 0.f, a1 = 0.f, a2 = 0.f, a3 = 0.f, a4 = 0.f;
  for (int jj = lane; jj < HH; jj += 64) {
    size_t idx = (size_t)t * HH + jj;
    float p = pooledPart[idx] + pooledPart[GS + idx]
            + pooledPart[2 * GS + idx] + pooledPart[3 * GS + idx];
    a0 += p * fcW[jj];
    a1 += p * fcW[512 + jj];
    a2 += p * fcW[1024 + jj];
    a3 += p * fcW[1536 + jj];
    a4 += p * fcW[2048 + jj];
  }
  #pragma unroll
  for (int off = 32; off > 0; off >>= 1) {
    a0 += __shfl_down(a0, off, 64);
    a1 += __shfl_down(a1, off, 64);
    a2 += __shfl_down(a2, off, 64);
    a3 += __shfl_down(a3, off, 64);
    a4 += __shfl_down(a4, off, 64);
  }
  if (lane == 0) {
    const float sc = 1.f / 64.f;
    out[t * 5 + 0] = a0 * sc + fcb[0];
    out[t * 5 + 1] = a1 * sc + fcb[1];
    out[t * 5 + 2] = a2 * sc + fcb[2];
    out[t * 5 + 3] = a3 * sc + fcb[3];
    out[t * 5 + 4] = a4 * sc + fcb[4];
  }
}

extern "C" void kernel_launch(void* const* d_in, const int* in_sizes, int n_in,
                              void* d_out, int out_size, void* d_ws, size_t ws_size,
                              hipStream_t stream) {
  const int*   texts = (const int*)  d_in[0];
  const float* emb   = (const float*)d_in[1];
  const float* Wih0  = (const float*)d_in[2];
  const float* Whh0  = (const float*)d_in[3];
  const float* bih0  = (const float*)d_in[4];
  const float* bhh0  = (const float*)d_in[5];
  const float* Wih1  = (const float*)d_in[6];
  const float* Whh1  = (const float*)d_in[7];
  const float* bih1  = (const float*)d_in[8];
  const float* bhh1  = (const float*)d_in[9];
  const float* fcW   = (const float*)d_in[10];
  const float* fcb   = (const float*)d_in[11];
  float* out = (float*)d_out;

  char* ws = (char*)d_ws;
  int*      flags0   = (int*)ws;                     // 8192 B (4 grp x 32 x 64B)
  int*      flagsP0  = (int*)(ws + 8192);            // 8192 B
  int*      flagsP1  = (int*)(ws + 16384);           // 8192 B
  int*      flags1   = (int*)(ws + 24576);           // 8192 B
  float*    pooledPt = (float*)(ws + 32768);         // 4194304 B [4][512][512] f32
  _Float16* h1seq    = (_Float16*)(ws + 4227072);    // 33554432 B (512 x 64KB, write-once)
  _Float16* h2seq    = (_Float16*)(ws + 37781504);   // 33554432 B (512 x 64KB, write-once)
  float*    xp1ring  = (float*)(ws + 71335936);      // 2097152 B (4 x 512KB)
  float*    xp0ring  = (float*)(ws + 73433088);      // 8388608 B (16 x 512KB)
  _Float16* x0       = (_Float16*)(ws + 81821696);   // 20971520 B [512][64][320]
  float*    bias0    = (float*)(ws + 102793216);     // 8192 B (r,z,nx,nh)
  float*    bias1    = (float*)(ws + 102801408);     // 8192 B
  // total ws use: 102809600 B

  hipMemsetAsync(ws, 0, 32768, stream);  // flags only (pooledPart fully overwritten)
  prep_x0<<<4096, 256, 0, stream>>>(texts, emb, x0);
  prep_b<<<2, 256, 0, stream>>>(bih0, bhh0, bih1, bhh1, bias0, bias1);
  gru_persistent<<<128, 256, 0, stream>>>(x0, Wih0, Whh0, Wih1, Whh1, bias0, bias1,
                                          h1seq, h2seq, xp0ring, xp1ring, pooledPt,
                                          flags0, flagsP0, flagsP1, flags1);
  fc_kernel<<<512, 64, 0, stream>>>(pooledPt, fcW, fcb, out);
}